// Round 9
// baseline (2799.443 us; speedup 1.0000x reference)
//
#include <hip/hip_runtime.h>

#define EMB 64
#define INDIM 140
#define NL 4
#define EPS 1e-5f

// padded stats: value v lives at st[v*16] (one 64B line per value)
__device__ __forceinline__ float bnrelu(float v, float sum, float sq, float g, float be, float invN){
  float mu  = sum*invN;
  float var = fmaf(-mu, mu, sq*invN);
  float sc  = g * rsqrtf(var + EPS);
  return fmaxf(fmaf(v - mu, sc, be), 0.f);
}

// ---- fused: deg histogram + edge_attr moments ----
__global__ __launch_bounds__(256) void k_pass1(const int* __restrict__ dst,
    const float* __restrict__ ea, int E, int* __restrict__ deg, float* __restrict__ est)
{
  __shared__ float ls[9];
  if (threadIdx.x < 9) ls[threadIdx.x] = 0.f;
  __syncthreads();
  int tid = blockIdx.x*blockDim.x + threadIdx.x;
  int stride = gridDim.x*blockDim.x;
  float a0=0,a1=0,a2=0,p00=0,p11=0,p22=0,p01=0,p02=0,p12=0;
  for (int e=tid;e<E;e+=stride){
    atomicAdd(&deg[dst[e]],1);
    float d0=ea[3*e+0], d1=ea[3*e+1], d2=ea[3*e+2];
    a0+=d0;a1+=d1;a2+=d2;
    p00=fmaf(d0,d0,p00); p11=fmaf(d1,d1,p11); p22=fmaf(d2,d2,p22);
    p01=fmaf(d0,d1,p01); p02=fmaf(d0,d2,p02); p12=fmaf(d1,d2,p12);
  }
  #pragma unroll
  for (int off=32; off>0; off>>=1){
    a0+=__shfl_down(a0,off); a1+=__shfl_down(a1,off); a2+=__shfl_down(a2,off);
    p00+=__shfl_down(p00,off); p11+=__shfl_down(p11,off); p22+=__shfl_down(p22,off);
    p01+=__shfl_down(p01,off); p02+=__shfl_down(p02,off); p12+=__shfl_down(p12,off);
  }
  if ((threadIdx.x & 63)==0){
    atomicAdd(&ls[0],a0); atomicAdd(&ls[1],a1); atomicAdd(&ls[2],a2);
    atomicAdd(&ls[3],p00); atomicAdd(&ls[4],p11); atomicAdd(&ls[5],p22);
    atomicAdd(&ls[6],p01); atomicAdd(&ls[7],p02); atomicAdd(&ls[8],p12);
  }
  __syncthreads();
  if (threadIdx.x < 9) atomicAdd(&est[threadIdx.x*16], ls[threadIdx.x]);
}

// ---- hierarchical scan ----
__global__ __launch_bounds__(256) void k_scanA(const int* __restrict__ deg,
    int* __restrict__ bsum, int n)
{
  int b = blockIdx.x, t = threadIdx.x;
  int i0 = b*1024 + t*4;
  int s = 0;
  if (i0+3 < n){ int4 v = *(const int4*)(deg+i0); s = v.x+v.y+v.z+v.w; }
  else { for (int j=0;j<4;j++){ int i=i0+j; if (i<n) s += deg[i]; } }
  #pragma unroll
  for (int off=32;off>0;off>>=1) s += __shfl_down(s, off);
  __shared__ int ws[4];
  if ((t&63)==0) ws[t>>6] = s;
  __syncthreads();
  if (t==0) bsum[b] = ws[0]+ws[1]+ws[2]+ws[3];
}

__global__ __launch_bounds__(64) void k_scanB(const int* __restrict__ bsum,
    int* __restrict__ boff, int* __restrict__ rs, int nb, int n)
{
  int t = threadIdx.x;
  int carry = 0;
  for (int base=0; base<nb; base+=64){
    int idx = base + t;
    int v = (idx<nb)? bsum[idx] : 0;
    int x = v;
    #pragma unroll
    for (int off=1;off<64;off<<=1){ int u = __shfl_up(x, off); if (t>=off) x += u; }
    if (idx<nb) boff[idx] = carry + x - v;
    int tot = __shfl(x, 63);
    carry += tot;
  }
  if (t==0) rs[n] = carry;
}

__global__ __launch_bounds__(256) void k_scanC(int* __restrict__ deg,
    const int* __restrict__ boff, int* __restrict__ rs, int n)
{
  int b = blockIdx.x, t = threadIdx.x;
  int i0 = b*1024 + t*4;
  int a=0,c=0,d=0,e=0;
  if (i0+3 < n){ int4 v = *(const int4*)(deg+i0); a=v.x;c=v.y;d=v.z;e=v.w; }
  else { if(i0<n)a=deg[i0]; if(i0+1<n)c=deg[i0+1]; if(i0+2<n)d=deg[i0+2]; if(i0+3<n)e=deg[i0+3]; }
  int s4 = a+c+d+e;
  int x = s4;
  int lane = t & 63;
  #pragma unroll
  for (int off=1;off<64;off<<=1){ int u = __shfl_up(x, off); if (lane>=off) x += u; }
  int wexcl = x - s4;
  __shared__ int ws[4];
  if (lane==63) ws[t>>6] = x;
  __syncthreads();
  int base = boff[b];
  int wid = t>>6;
  for (int j=0;j<wid;j++) base += ws[j];
  int p = base + wexcl;
  int r0=p, r1=p+a, r2=p+a+c, r3=p+a+c+d;
  if (i0+3 < n){
    *(int4*)(rs+i0)  = make_int4(r0,r1,r2,r3);
    *(int4*)(deg+i0) = make_int4(r0,r1,r2,r3);
  } else {
    if(i0<n){rs[i0]=r0;deg[i0]=r0;} if(i0+1<n){rs[i0+1]=r1;deg[i0+1]=r1;}
    if(i0+2<n){rs[i0+2]=r2;deg[i0+2]=r2;} if(i0+3<n){rs[i0+3]=r3;deg[i0+3]=r3;}
  }
}

// ---- scatter edges into dst-sorted 16B records {d0,d1,d2,(float)src} ----
__global__ __launch_bounds__(256) void k_scatter(const int* __restrict__ src,
    const int* __restrict__ dst, const float* __restrict__ ea, int E,
    int* __restrict__ cur, float4* __restrict__ rec)
{
  int tid = blockIdx.x*blockDim.x + threadIdx.x;
  int stride = gridDim.x*blockDim.x;
  for (int e=tid;e<E;e+=stride){
    int d = dst[e];
    int p = atomicAdd(&cur[d], 1);
    rec[p] = make_float4(ea[3*e+0], ea[3*e+1], ea[3*e+2], (float)src[e]);
  }
}

// ---- fold edge-BN into affine A,c per layer/channel ----
__global__ __launch_bounds__(256) void k_prec(const float* __restrict__ est,
  const float* __restrict__ w1, const float* __restrict__ b1,
  const float* __restrict__ g1, const float* __restrict__ be1,
  float* __restrict__ ac, float invE)
{
  int t = threadIdx.x; int l = t>>6, c = t&63;
  float m0 = est[0]*invE, m1 = est[16]*invE, m2 = est[32]*invE;
  float c00 = est[48]*invE - m0*m0, c11 = est[64]*invE - m1*m1, c22 = est[80]*invE - m2*m2;
  float c01 = est[96]*invE - m0*m1, c02 = est[112]*invE - m0*m2, c12 = est[128]*invE - m1*m2;
  float w0 = w1[(l*3+0)*64+c], w1_ = w1[(l*3+1)*64+c], w2_ = w1[(l*3+2)*64+c];
  float b = b1[l*64+c], g = g1[l*64+c], be = be1[l*64+c];
  float mu = m0*w0 + m1*w1_ + m2*w2_ + b;
  float var = w0*w0*c00 + w1_*w1_*c11 + w2_*w2_*c22
            + 2.f*(w0*w1_*c01 + w0*w2_*c02 + w1_*w2_*c12);
  float sc = g * rsqrtf(var + EPS);
  float* o = ac + l*256 + c*4;
  o[0] = w0*sc; o[1] = w1_*sc; o[2] = w2_*sc; o[3] = (b - mu)*sc + be;
}

// ---- h0 = x @ lin_in_w + b : 8 nodes/wave, x rows staged in LDS,
//      weights loaded once per k-chunk and reused 8x ----
__global__ __launch_bounds__(256) void k_h0(const float* __restrict__ x,
  const float* __restrict__ w, const float* __restrict__ b, float* __restrict__ h, int n)
{
  __shared__ float4 s_x[4][280];            // 4 waves x (8 rows x 35 float4)
  int wv = (blockIdx.x*256 + threadIdx.x) >> 6;
  int wslot = (threadIdx.x >> 6) & 3;
  int lane = threadIdx.x & 63;
  int i0 = wv*8;
  int m = n - i0; if (m > 8) m = 8; if (m < 0) m = 0;
  int limit = m*35;
  const float4* xp4 = (const float4*)(x + (size_t)i0*INDIM);
  #pragma unroll
  for (int j=0;j<5;j++){
    int idx = j*64 + lane;
    if (idx < limit) s_x[wslot][idx] = xp4[idx];
  }
  __syncthreads();
  float acc[8];
  float bl = b[lane];
  #pragma unroll
  for (int t=0;t<8;t++) acc[t] = bl;
  const float* wcol = w + lane;
  #pragma unroll
  for (int kq=0; kq<35; kq++){
    float w0 = wcol[(4*kq+0)*EMB];
    float w1 = wcol[(4*kq+1)*EMB];
    float w2 = wcol[(4*kq+2)*EMB];
    float w3 = wcol[(4*kq+3)*EMB];
    #pragma unroll
    for (int t=0;t<8;t++){
      float4 xv = s_x[wslot][t*35 + kq];
      acc[t] = fmaf(xv.x, w0, acc[t]);
      acc[t] = fmaf(xv.y, w1, acc[t]);
      acc[t] = fmaf(xv.z, w2, acc[t]);
      acc[t] = fmaf(xv.w, w3, acc[t]);
    }
  }
  #pragma unroll
  for (int t=0;t<8;t++)
    if (t < m) h[(size_t)(i0+t)*EMB + lane] = acc[t];
}

// ---- fused per-layer stage 1: h update + edge encoder + r@w2 -> hh
//      4 nodes/wave; weight loads amortized 4x ----
__global__ __launch_bounds__(256) void k_l1(
  float* __restrict__ h, float* __restrict__ hh, const float* __restrict__ yprev,
  const int* __restrict__ rs, const float4* __restrict__ rec,
  const float* __restrict__ ac, const float* __restrict__ w2, const float* __restrict__ b2,
  const float* __restrict__ st2, const float* __restrict__ g2, const float* __restrict__ be2,
  int n, int update, float invN)
{
  __shared__ float4 ldsr[4][4][16];         // [wave][node][16 float4]
  int wv = (blockIdx.x*256 + threadIdx.x) >> 6;
  int wslot = (threadIdx.x >> 6) & 3;
  int lane = threadIdx.x & 63;
  int i0 = wv*4;
  float4 a = ((const float4*)ac)[lane];
  float b2l = b2[lane];
  float accv[4];
  #pragma unroll
  for (int t=0;t<4;t++){
    int i = i0 + t;
    bool act = (i < n);
    int ii = act ? i : 0;
    int e0 = rs[ii], e1 = rs[ii+1];         // vector loads (per-call-varying data)
    float racc = 0.f;
    int e = e0;
    for (; e+4<=e1; e+=4){
      float4 d0 = rec[e], d1 = rec[e+1], d2 = rec[e+2], d3 = rec[e+3];
      racc += fmaxf(fmaf(d0.x,a.x,fmaf(d0.y,a.y,fmaf(d0.z,a.z,a.w))),0.f);
      racc += fmaxf(fmaf(d1.x,a.x,fmaf(d1.y,a.y,fmaf(d1.z,a.z,a.w))),0.f);
      racc += fmaxf(fmaf(d2.x,a.x,fmaf(d2.y,a.y,fmaf(d2.z,a.z,a.w))),0.f);
      racc += fmaxf(fmaf(d3.x,a.x,fmaf(d3.y,a.y,fmaf(d3.z,a.z,a.w))),0.f);
    }
    for (; e<e1; e++){
      float4 d0 = rec[e];
      racc += fmaxf(fmaf(d0.x,a.x,fmaf(d0.y,a.y,fmaf(d0.z,a.z,a.w))),0.f);
    }
    ((float*)&ldsr[wslot][t])[lane] = racc;
    float hv = h[(size_t)ii*EMB + lane];
    if (update){
      float yv = yprev[(size_t)ii*EMB + lane];
      hv += bnrelu(yv, st2[lane*16], st2[(64+lane)*16], g2[lane], be2[lane], invN);
      if (act) h[(size_t)i*EMB + lane] = hv;
    }
    float degf = (float)(e1 - e0);
    accv[t] = fmaf(degf, b2l, hv);
  }
  __syncthreads();
  const float* wcol = w2 + lane;
  #pragma unroll
  for (int kq=0; kq<16; kq++){
    float w0 = wcol[(4*kq+0)*EMB];
    float w1v = wcol[(4*kq+1)*EMB];
    float w2v = wcol[(4*kq+2)*EMB];
    float w3 = wcol[(4*kq+3)*EMB];
    #pragma unroll
    for (int t=0;t<4;t++){
      float4 rv = ldsr[wslot][t][kq];
      accv[t] = fmaf(rv.x, w0, accv[t]);
      accv[t] = fmaf(rv.y, w1v, accv[t]);
      accv[t] = fmaf(rv.z, w2v, accv[t]);
      accv[t] = fmaf(rv.w, w3, accv[t]);
    }
  }
  #pragma unroll
  for (int t=0;t<4;t++)
    if (i0+t < n) hh[(size_t)(i0+t)*EMB + lane] = accv[t];
}

// ---- fused per-layer stage 2: gather + (hh+msg)@w1 + b1 -> y ----
__global__ __launch_bounds__(256) void k_l2(
  const float* __restrict__ hh, const int* __restrict__ rs, const float* __restrict__ recw,
  const float* __restrict__ w1, const float* __restrict__ b1,
  float* __restrict__ y, int n)
{
  __shared__ float4 ldsz[4][4][16];
  int wv = (blockIdx.x*256 + threadIdx.x) >> 6;
  int wslot = (threadIdx.x >> 6) & 3;
  int lane = threadIdx.x & 63;
  int i0 = wv*4;
  #pragma unroll
  for (int t=0;t<4;t++){
    int i = i0 + t;
    bool act = (i < n);
    int ii = act ? i : 0;
    int e0 = rs[ii], e1 = rs[ii+1];
    float zc = hh[(size_t)ii*EMB + lane];
    int e = e0;
    for (; e+4<=e1; e+=4){
      int s0 = (int)recw[4*e+3];
      int s1 = (int)recw[4*e+7];
      int s2 = (int)recw[4*e+11];
      int s3 = (int)recw[4*e+15];
      zc += hh[(size_t)s0*EMB + lane];
      zc += hh[(size_t)s1*EMB + lane];
      zc += hh[(size_t)s2*EMB + lane];
      zc += hh[(size_t)s3*EMB + lane];
    }
    for (; e<e1; e++){
      int s0 = (int)recw[4*e+3];
      zc += hh[(size_t)s0*EMB + lane];
    }
    ((float*)&ldsz[wslot][t])[lane] = zc;
  }
  __syncthreads();
  float b1l = b1[lane];
  float accv[4];
  #pragma unroll
  for (int t=0;t<4;t++) accv[t] = b1l;
  const float* wcol = w1 + lane;
  #pragma unroll
  for (int kq=0; kq<16; kq++){
    float w0 = wcol[(4*kq+0)*EMB];
    float w1v = wcol[(4*kq+1)*EMB];
    float w2v = wcol[(4*kq+2)*EMB];
    float w3 = wcol[(4*kq+3)*EMB];
    #pragma unroll
    for (int t=0;t<4;t++){
      float4 zv = ldsz[wslot][t][kq];
      accv[t] = fmaf(zv.x, w0, accv[t]);
      accv[t] = fmaf(zv.y, w1v, accv[t]);
      accv[t] = fmaf(zv.z, w2v, accv[t]);
      accv[t] = fmaf(zv.w, w3, accv[t]);
    }
  }
  #pragma unroll
  for (int t=0;t<4;t++)
    if (i0+t < n) y[(size_t)(i0+t)*EMB + lane] = accv[t];
}

// ---- per-layer stage 3: y = relu(bn1(y)) @ w2m + b2 (in place) ----
__global__ __launch_bounds__(256) void k_l3(float* __restrict__ y,
  const float* __restrict__ st1, const float* __restrict__ g1, const float* __restrict__ be1,
  const float* __restrict__ w2, const float* __restrict__ b2, int n, float invN)
{
  __shared__ float4 ldst[4][4][16];
  int wv = (blockIdx.x*256 + threadIdx.x) >> 6;
  int wslot = (threadIdx.x >> 6) & 3;
  int lane = threadIdx.x & 63;
  int i0 = wv*4;
  float s1 = st1[lane*16], sq1 = st1[(64+lane)*16];
  float g1l = g1[lane], be1l = be1[lane];
  #pragma unroll
  for (int t=0;t<4;t++){
    int i = i0 + t;
    int ii = (i < n) ? i : 0;
    float yv = y[(size_t)ii*EMB + lane];
    ((float*)&ldst[wslot][t])[lane] = bnrelu(yv, s1, sq1, g1l, be1l, invN);
  }
  __syncthreads();
  float b2l = b2[lane];
  float accv[4];
  #pragma unroll
  for (int t=0;t<4;t++) accv[t] = b2l;
  const float* wcol = w2 + lane;
  #pragma unroll
  for (int kq=0; kq<16; kq++){
    float w0 = wcol[(4*kq+0)*EMB];
    float w1v = wcol[(4*kq+1)*EMB];
    float w2v = wcol[(4*kq+2)*EMB];
    float w3 = wcol[(4*kq+3)*EMB];
    #pragma unroll
    for (int t=0;t<4;t++){
      float4 tv = ldst[wslot][t][kq];
      accv[t] = fmaf(tv.x, w0, accv[t]);
      accv[t] = fmaf(tv.y, w1v, accv[t]);
      accv[t] = fmaf(tv.z, w2v, accv[t]);
      accv[t] = fmaf(tv.w, w3, accv[t]);
    }
  }
  #pragma unroll
  for (int t=0;t<4;t++)
    if (i0+t < n) y[(size_t)(i0+t)*EMB + lane] = accv[t];
}

// ---- per-channel sum/sumsq -> padded atomics into st (st pre-zeroed) ----
__global__ __launch_bounds__(256) void k_stats(const float* __restrict__ y,
    float* __restrict__ st, int n)
{
  __shared__ float ls[128];
  int lane = threadIdx.x & 63;
  int wid  = threadIdx.x >> 6;
  int gw = blockIdx.x*4 + wid;
  int nw = gridDim.x*4;
  float s=0.f, q=0.f;
  for (int i=gw; i<n; i+=nw){
    float v = y[(size_t)i*EMB + lane];
    s += v; q = fmaf(v,v,q);
  }
  if (threadIdx.x < 128) ls[threadIdx.x] = 0.f;
  __syncthreads();
  atomicAdd(&ls[lane], s); atomicAdd(&ls[64+lane], q);
  __syncthreads();
  if (threadIdx.x < 128) atomicAdd(&st[threadIdx.x*16], ls[threadIdx.x]);
}

// ---- final: h4 = h3 + relu(bn2(y)); out = h4 . wp + bp ----
__global__ __launch_bounds__(64) void k_out(
  const float* __restrict__ h, const float* __restrict__ y,
  const float* __restrict__ st2, const float* __restrict__ g2, const float* __restrict__ be2,
  const float* __restrict__ wp, const float* __restrict__ bp,
  float* __restrict__ out, int n, float invN)
{
  int i = blockIdx.x*64 + threadIdx.x; if (i>=n) return;
  const float* hr = h + (size_t)i*EMB;
  const float* yr = y + (size_t)i*EMB;
  float acc = 0.f;
  #pragma unroll
  for (int q=0;q<16;q++){
    int c0=q*4;
    float4 hv = *(const float4*)(hr+c0);
    float4 yv = *(const float4*)(yr+c0);
    float f0 = hv.x + bnrelu(yv.x, st2[(c0+0)*16], st2[(64+c0+0)*16], g2[c0+0], be2[c0+0], invN);
    float f1 = hv.y + bnrelu(yv.y, st2[(c0+1)*16], st2[(64+c0+1)*16], g2[c0+1], be2[c0+1], invN);
    float f2 = hv.z + bnrelu(yv.z, st2[(c0+2)*16], st2[(64+c0+2)*16], g2[c0+2], be2[c0+2], invN);
    float f3 = hv.w + bnrelu(yv.w, st2[(c0+3)*16], st2[(64+c0+3)*16], g2[c0+3], be2[c0+3], invN);
    acc = fmaf(f0, wp[c0+0], acc);
    acc = fmaf(f1, wp[c0+1], acc);
    acc = fmaf(f2, wp[c0+2], acc);
    acc = fmaf(f3, wp[c0+3], acc);
  }
  out[i] = acc + bp[0];
}

extern "C" void kernel_launch(void* const* d_in, const int* in_sizes, int n_in,
                              void* d_out, int out_size, void* d_ws, size_t ws_size,
                              hipStream_t stream)
{
  const float* x        = (const float*)d_in[0];
  const int*   ei       = (const int*)d_in[1];
  const float* ea       = (const float*)d_in[2];
  const float* lin_in_w = (const float*)d_in[3];
  const float* lin_in_b = (const float*)d_in[4];
  const float* ee_w1    = (const float*)d_in[5];
  const float* ee_b1    = (const float*)d_in[6];
  const float* ee_g1    = (const float*)d_in[7];
  const float* ee_be1   = (const float*)d_in[8];
  const float* ee_w2    = (const float*)d_in[9];
  const float* ee_b2    = (const float*)d_in[10];
  const float* mlp_w1   = (const float*)d_in[11];
  const float* mlp_b1   = (const float*)d_in[12];
  const float* mlp_g1   = (const float*)d_in[13];
  const float* mlp_be1  = (const float*)d_in[14];
  const float* mlp_w2   = (const float*)d_in[15];
  const float* mlp_b2   = (const float*)d_in[16];
  const float* mlp_g2   = (const float*)d_in[17];
  const float* mlp_be2  = (const float*)d_in[18];
  const float* pred_w   = (const float*)d_in[19];
  const float* pred_b   = (const float*)d_in[20];

  int n = in_sizes[0] / INDIM;
  int E = in_sizes[1] / 2;
  const int* srcp = ei;
  const int* dstp = ei + E;

  char* w = (char*)d_ws;
  auto al = [](size_t o){ return (o + 255) & ~(size_t)255; };
  size_t o = 0;
  int*   deg = (int*)(w + o);  o += (size_t)n*4;  o = al(o);
  float* est = (float*)(w + o); o += 144*4;  o = al(o);
  float* nst = (float*)(w + o); o += (size_t)NL*2*2048*4;   // per layer: st1[2048], st2[2048] (16-padded)
  size_t zero_bytes = o;
  o = al(o); int* rs   = (int*)(w + o);   o += (size_t)(n+1)*4;
  o = al(o); int* bsum = (int*)(w + o);   o += 256*4;
  o = al(o); int* boff = (int*)(w + o);   o += 256*4;
  o = al(o); float4* rec = (float4*)(w + o); o += (size_t)E*16;
  o = al(o); float* acb = (float*)(w + o); o += (size_t)NL*256*4;
  o = al(o); float* h   = (float*)(w + o); o += (size_t)n*EMB*4;
  o = al(o); float* hhb = (float*)(w + o); o += (size_t)n*EMB*4;
  o = al(o); float* yb  = (float*)(w + o); o += (size_t)n*EMB*4;

  (void)hipMemsetAsync(d_ws, 0, zero_bytes, stream);

  int nbChunk = (n + 1023)/1024;
  k_pass1<<<512, 256, 0, stream>>>(dstp, ea, E, deg, est);
  k_scanA<<<nbChunk, 256, 0, stream>>>(deg, bsum, n);
  k_scanB<<<1, 64, 0, stream>>>(bsum, boff, rs, nbChunk, n);
  k_scanC<<<nbChunk, 256, 0, stream>>>(deg, boff, rs, n);
  k_scatter<<<1024, 256, 0, stream>>>(srcp, dstp, ea, E, deg /*cur*/, rec);
  k_prec<<<1, 256, 0, stream>>>(est, ee_w1, ee_b1, ee_g1, ee_be1, acb, 1.f/(float)E);

  int nb_h0 = ((n + 7)/8 + 3)/4;        // 8 nodes/wave, 4 waves/block
  int nb_l  = (n + 15)/16;              // 4 nodes/wave, 4 waves/block
  float invN = 1.f/(float)n;
  k_h0<<<nb_h0, 256, 0, stream>>>(x, lin_in_w, lin_in_b, h, n);

  for (int l=0; l<NL; l++){
    float* st1 = nst + (size_t)l*4096;
    float* st2 = st1 + 2048;
    const float* st2prev = (l>0) ? (nst + (size_t)(l-1)*4096 + 2048) : nst;
    const float* g2p  = (l>0) ? (mlp_g2  + (size_t)(l-1)*64) : mlp_g2;
    const float* be2p = (l>0) ? (mlp_be2 + (size_t)(l-1)*64) : mlp_be2;
    k_l1<<<nb_l, 256, 0, stream>>>(h, hhb, yb, rs, rec,
        acb + (size_t)l*256, ee_w2 + (size_t)l*4096, ee_b2 + (size_t)l*64,
        st2prev, g2p, be2p, n, (l>0)?1:0, invN);
    k_l2<<<nb_l, 256, 0, stream>>>(hhb, rs, (const float*)rec,
        mlp_w1 + (size_t)l*4096, mlp_b1 + (size_t)l*64, yb, n);
    k_stats<<<256, 256, 0, stream>>>(yb, st1, n);
    k_l3<<<nb_l, 256, 0, stream>>>(yb, st1,
        mlp_g1 + (size_t)l*64, mlp_be1 + (size_t)l*64,
        mlp_w2 + (size_t)l*4096, mlp_b2 + (size_t)l*64, n, invN);
    k_stats<<<256, 256, 0, stream>>>(yb, st2, n);
  }
  k_out<<<(n+63)/64, 64, 0, stream>>>(h, yb,
      nst + (size_t)(NL-1)*4096 + 2048, mlp_g2 + (size_t)(NL-1)*64, mlp_be2 + (size_t)(NL-1)*64,
      pred_w, pred_b, (float*)d_out, n, invN);
}

// Round 10
// 1000.528 us; speedup vs baseline: 2.7980x; 2.7980x over previous
//
#include <hip/hip_runtime.h>

#define EMB 64
#define INDIM 140
#define NL 4
#define EPS 1e-5f

// padded stats: value v lives at st[v*16] (one 64B line per value)
__device__ __forceinline__ float bnrelu(float v, float sum, float sq, float g, float be, float invN){
  float mu  = sum*invN;
  float var = fmaf(-mu, mu, sq*invN);
  float sc  = g * rsqrtf(var + EPS);
  return fmaxf(fmaf(v - mu, sc, be), 0.f);
}

// ---- fused: deg histogram + edge_attr moments ----
__global__ __launch_bounds__(256) void k_pass1(const int* __restrict__ dst,
    const float* __restrict__ ea, int E, int* __restrict__ deg, float* __restrict__ est)
{
  __shared__ float ls[9];
  if (threadIdx.x < 9) ls[threadIdx.x] = 0.f;
  __syncthreads();
  int tid = blockIdx.x*blockDim.x + threadIdx.x;
  int stride = gridDim.x*blockDim.x;
  float a0=0,a1=0,a2=0,p00=0,p11=0,p22=0,p01=0,p02=0,p12=0;
  for (int e=tid;e<E;e+=stride){
    atomicAdd(&deg[dst[e]],1);
    float d0=ea[3*e+0], d1=ea[3*e+1], d2=ea[3*e+2];
    a0+=d0;a1+=d1;a2+=d2;
    p00=fmaf(d0,d0,p00); p11=fmaf(d1,d1,p11); p22=fmaf(d2,d2,p22);
    p01=fmaf(d0,d1,p01); p02=fmaf(d0,d2,p02); p12=fmaf(d1,d2,p12);
  }
  #pragma unroll
  for (int off=32; off>0; off>>=1){
    a0+=__shfl_down(a0,off); a1+=__shfl_down(a1,off); a2+=__shfl_down(a2,off);
    p00+=__shfl_down(p00,off); p11+=__shfl_down(p11,off); p22+=__shfl_down(p22,off);
    p01+=__shfl_down(p01,off); p02+=__shfl_down(p02,off); p12+=__shfl_down(p12,off);
  }
  if ((threadIdx.x & 63)==0){
    atomicAdd(&ls[0],a0); atomicAdd(&ls[1],a1); atomicAdd(&ls[2],a2);
    atomicAdd(&ls[3],p00); atomicAdd(&ls[4],p11); atomicAdd(&ls[5],p22);
    atomicAdd(&ls[6],p01); atomicAdd(&ls[7],p02); atomicAdd(&ls[8],p12);
  }
  __syncthreads();
  if (threadIdx.x < 9) atomicAdd(&est[threadIdx.x*16], ls[threadIdx.x]);
}

// ---- hierarchical scan ----
__global__ __launch_bounds__(256) void k_scanA(const int* __restrict__ deg,
    int* __restrict__ bsum, int n)
{
  int b = blockIdx.x, t = threadIdx.x;
  int i0 = b*1024 + t*4;
  int s = 0;
  if (i0+3 < n){ int4 v = *(const int4*)(deg+i0); s = v.x+v.y+v.z+v.w; }
  else { for (int j=0;j<4;j++){ int i=i0+j; if (i<n) s += deg[i]; } }
  #pragma unroll
  for (int off=32;off>0;off>>=1) s += __shfl_down(s, off);
  __shared__ int ws[4];
  if ((t&63)==0) ws[t>>6] = s;
  __syncthreads();
  if (t==0) bsum[b] = ws[0]+ws[1]+ws[2]+ws[3];
}

__global__ __launch_bounds__(64) void k_scanB(const int* __restrict__ bsum,
    int* __restrict__ boff, int* __restrict__ rs, int nb, int n)
{
  int t = threadIdx.x;
  int carry = 0;
  for (int base=0; base<nb; base+=64){
    int idx = base + t;
    int v = (idx<nb)? bsum[idx] : 0;
    int x = v;
    #pragma unroll
    for (int off=1;off<64;off<<=1){ int u = __shfl_up(x, off); if (t>=off) x += u; }
    if (idx<nb) boff[idx] = carry + x - v;
    int tot = __shfl(x, 63);
    carry += tot;
  }
  if (t==0) rs[n] = carry;
}

__global__ __launch_bounds__(256) void k_scanC(int* __restrict__ deg,
    const int* __restrict__ boff, int* __restrict__ rs, int n)
{
  int b = blockIdx.x, t = threadIdx.x;
  int i0 = b*1024 + t*4;
  int a=0,c=0,d=0,e=0;
  if (i0+3 < n){ int4 v = *(const int4*)(deg+i0); a=v.x;c=v.y;d=v.z;e=v.w; }
  else { if(i0<n)a=deg[i0]; if(i0+1<n)c=deg[i0+1]; if(i0+2<n)d=deg[i0+2]; if(i0+3<n)e=deg[i0+3]; }
  int s4 = a+c+d+e;
  int x = s4;
  int lane = t & 63;
  #pragma unroll
  for (int off=1;off<64;off<<=1){ int u = __shfl_up(x, off); if (lane>=off) x += u; }
  int wexcl = x - s4;
  __shared__ int ws[4];
  if (lane==63) ws[t>>6] = x;
  __syncthreads();
  int base = boff[b];
  int wid = t>>6;
  for (int j=0;j<wid;j++) base += ws[j];
  int p = base + wexcl;
  int r0=p, r1=p+a, r2=p+a+c, r3=p+a+c+d;
  if (i0+3 < n){
    *(int4*)(rs+i0)  = make_int4(r0,r1,r2,r3);
    *(int4*)(deg+i0) = make_int4(r0,r1,r2,r3);
  } else {
    if(i0<n){rs[i0]=r0;deg[i0]=r0;} if(i0+1<n){rs[i0+1]=r1;deg[i0+1]=r1;}
    if(i0+2<n){rs[i0+2]=r2;deg[i0+2]=r2;} if(i0+3<n){rs[i0+3]=r3;deg[i0+3]=r3;}
  }
}

// ---- scatter edges into dst-sorted 16B records {d0,d1,d2,(float)src} ----
__global__ __launch_bounds__(256) void k_scatter(const int* __restrict__ src,
    const int* __restrict__ dst, const float* __restrict__ ea, int E,
    int* __restrict__ cur, float4* __restrict__ rec)
{
  int tid = blockIdx.x*blockDim.x + threadIdx.x;
  int stride = gridDim.x*blockDim.x;
  for (int e=tid;e<E;e+=stride){
    int d = dst[e];
    int p = atomicAdd(&cur[d], 1);
    rec[p] = make_float4(ea[3*e+0], ea[3*e+1], ea[3*e+2], (float)src[e]);
  }
}

// ---- fold edge-BN into affine A,c per layer/channel ----
__global__ __launch_bounds__(256) void k_prec(const float* __restrict__ est,
  const float* __restrict__ w1, const float* __restrict__ b1,
  const float* __restrict__ g1, const float* __restrict__ be1,
  float* __restrict__ ac, float invE)
{
  int t = threadIdx.x; int l = t>>6, c = t&63;
  float m0 = est[0]*invE, m1 = est[16]*invE, m2 = est[32]*invE;
  float c00 = est[48]*invE - m0*m0, c11 = est[64]*invE - m1*m1, c22 = est[80]*invE - m2*m2;
  float c01 = est[96]*invE - m0*m1, c02 = est[112]*invE - m0*m2, c12 = est[128]*invE - m1*m2;
  float w0 = w1[(l*3+0)*64+c], w1_ = w1[(l*3+1)*64+c], w2_ = w1[(l*3+2)*64+c];
  float b = b1[l*64+c], g = g1[l*64+c], be = be1[l*64+c];
  float mu = m0*w0 + m1*w1_ + m2*w2_ + b;
  float var = w0*w0*c00 + w1_*w1_*c11 + w2_*w2_*c22
            + 2.f*(w0*w1_*c01 + w0*w2_*c02 + w1_*w2_*c12);
  float sc = g * rsqrtf(var + EPS);
  float* o = ac + l*256 + c*4;
  o[0] = w0*sc; o[1] = w1_*sc; o[2] = w2_*sc; o[3] = (b - mu)*sc + be;
}

// ---- h0 = x @ lin_in_w + b : 8 nodes/wave, x rows staged in LDS,
//      weights loaded once per k-chunk, reused 8x.
//      kq loop NOT unrolled: bounded live ranges (r9: full unroll -> 256 VGPR,
//      1.7GB scratch thrash). TLP hides per-iter latency. ----
__global__ __launch_bounds__(256) void k_h0(const float* __restrict__ x,
  const float* __restrict__ w, const float* __restrict__ b, float* __restrict__ h, int n)
{
  __shared__ float4 s_x[4][280];            // 4 waves x (8 rows x 35 float4)
  int wv = (blockIdx.x*256 + threadIdx.x) >> 6;
  int wslot = (threadIdx.x >> 6) & 3;
  int lane = threadIdx.x & 63;
  int i0 = wv*8;
  int m = n - i0; if (m > 8) m = 8; if (m < 0) m = 0;
  int limit = m*35;
  const float4* xp4 = (const float4*)(x + (size_t)i0*INDIM);
  #pragma unroll
  for (int j=0;j<5;j++){
    int idx = j*64 + lane;
    if (idx < limit) s_x[wslot][idx] = xp4[idx];
  }
  __syncthreads();
  float acc[8];
  float bl = b[lane];
  #pragma unroll
  for (int t=0;t<8;t++) acc[t] = bl;
  const float* wcol = w + lane;
  #pragma unroll 1
  for (int kq=0; kq<35; kq++){
    float w0 = wcol[(4*kq+0)*EMB];
    float w1 = wcol[(4*kq+1)*EMB];
    float w2 = wcol[(4*kq+2)*EMB];
    float w3 = wcol[(4*kq+3)*EMB];
    #pragma unroll
    for (int t=0;t<8;t++){
      float4 xv = s_x[wslot][t*35 + kq];
      acc[t] = fmaf(xv.x, w0, acc[t]);
      acc[t] = fmaf(xv.y, w1, acc[t]);
      acc[t] = fmaf(xv.z, w2, acc[t]);
      acc[t] = fmaf(xv.w, w3, acc[t]);
    }
  }
  #pragma unroll
  for (int t=0;t<8;t++)
    if (t < m) h[(size_t)(i0+t)*EMB + lane] = acc[t];
}

// ---- fused per-layer stage 1: h update + edge encoder + r@w2 -> hh
//      4 nodes/wave; kq loop not unrolled (live-range bound) ----
__global__ __launch_bounds__(256) void k_l1(
  float* __restrict__ h, float* __restrict__ hh, const float* __restrict__ yprev,
  const int* __restrict__ rs, const float4* __restrict__ rec,
  const float* __restrict__ ac, const float* __restrict__ w2, const float* __restrict__ b2,
  const float* __restrict__ st2, const float* __restrict__ g2, const float* __restrict__ be2,
  int n, int update, float invN)
{
  __shared__ float4 ldsr[4][4][16];         // [wave][node][16 float4]
  int wv = (blockIdx.x*256 + threadIdx.x) >> 6;
  int wslot = (threadIdx.x >> 6) & 3;
  int lane = threadIdx.x & 63;
  int i0 = wv*4;
  float4 a = ((const float4*)ac)[lane];
  float b2l = b2[lane];
  float accv[4];
  #pragma unroll
  for (int t=0;t<4;t++){
    int i = i0 + t;
    bool act = (i < n);
    int ii = act ? i : 0;
    int e0 = rs[ii], e1 = rs[ii+1];         // vector loads (per-call-varying data)
    float racc = 0.f;
    int e = e0;
    for (; e+4<=e1; e+=4){
      float4 d0 = rec[e], d1 = rec[e+1], d2 = rec[e+2], d3 = rec[e+3];
      racc += fmaxf(fmaf(d0.x,a.x,fmaf(d0.y,a.y,fmaf(d0.z,a.z,a.w))),0.f);
      racc += fmaxf(fmaf(d1.x,a.x,fmaf(d1.y,a.y,fmaf(d1.z,a.z,a.w))),0.f);
      racc += fmaxf(fmaf(d2.x,a.x,fmaf(d2.y,a.y,fmaf(d2.z,a.z,a.w))),0.f);
      racc += fmaxf(fmaf(d3.x,a.x,fmaf(d3.y,a.y,fmaf(d3.z,a.z,a.w))),0.f);
    }
    for (; e<e1; e++){
      float4 d0 = rec[e];
      racc += fmaxf(fmaf(d0.x,a.x,fmaf(d0.y,a.y,fmaf(d0.z,a.z,a.w))),0.f);
    }
    ((float*)&ldsr[wslot][t])[lane] = racc;
    float hv = h[(size_t)ii*EMB + lane];
    if (update){
      float yv = yprev[(size_t)ii*EMB + lane];
      hv += bnrelu(yv, st2[lane*16], st2[(64+lane)*16], g2[lane], be2[lane], invN);
      if (act) h[(size_t)i*EMB + lane] = hv;
    }
    float degf = (float)(e1 - e0);
    accv[t] = fmaf(degf, b2l, hv);
  }
  __syncthreads();
  const float* wcol = w2 + lane;
  #pragma unroll 1
  for (int kq=0; kq<16; kq++){
    float w0 = wcol[(4*kq+0)*EMB];
    float w1v = wcol[(4*kq+1)*EMB];
    float w2v = wcol[(4*kq+2)*EMB];
    float w3 = wcol[(4*kq+3)*EMB];
    #pragma unroll
    for (int t=0;t<4;t++){
      float4 rv = ldsr[wslot][t][kq];
      accv[t] = fmaf(rv.x, w0, accv[t]);
      accv[t] = fmaf(rv.y, w1v, accv[t]);
      accv[t] = fmaf(rv.z, w2v, accv[t]);
      accv[t] = fmaf(rv.w, w3, accv[t]);
    }
  }
  #pragma unroll
  for (int t=0;t<4;t++)
    if (i0+t < n) hh[(size_t)(i0+t)*EMB + lane] = accv[t];
}

// ---- fused per-layer stage 2: gather + (hh+msg)@w1 + b1 -> y ----
__global__ __launch_bounds__(256) void k_l2(
  const float* __restrict__ hh, const int* __restrict__ rs, const float* __restrict__ recw,
  const float* __restrict__ w1, const float* __restrict__ b1,
  float* __restrict__ y, int n)
{
  __shared__ float4 ldsz[4][4][16];
  int wv = (blockIdx.x*256 + threadIdx.x) >> 6;
  int wslot = (threadIdx.x >> 6) & 3;
  int lane = threadIdx.x & 63;
  int i0 = wv*4;
  #pragma unroll
  for (int t=0;t<4;t++){
    int i = i0 + t;
    bool act = (i < n);
    int ii = act ? i : 0;
    int e0 = rs[ii], e1 = rs[ii+1];
    float zc = hh[(size_t)ii*EMB + lane];
    int e = e0;
    for (; e+4<=e1; e+=4){
      int s0 = (int)recw[4*e+3];
      int s1 = (int)recw[4*e+7];
      int s2 = (int)recw[4*e+11];
      int s3 = (int)recw[4*e+15];
      zc += hh[(size_t)s0*EMB + lane];
      zc += hh[(size_t)s1*EMB + lane];
      zc += hh[(size_t)s2*EMB + lane];
      zc += hh[(size_t)s3*EMB + lane];
    }
    for (; e<e1; e++){
      int s0 = (int)recw[4*e+3];
      zc += hh[(size_t)s0*EMB + lane];
    }
    ((float*)&ldsz[wslot][t])[lane] = zc;
  }
  __syncthreads();
  float b1l = b1[lane];
  float accv[4];
  #pragma unroll
  for (int t=0;t<4;t++) accv[t] = b1l;
  const float* wcol = w1 + lane;
  #pragma unroll 1
  for (int kq=0; kq<16; kq++){
    float w0 = wcol[(4*kq+0)*EMB];
    float w1v = wcol[(4*kq+1)*EMB];
    float w2v = wcol[(4*kq+2)*EMB];
    float w3 = wcol[(4*kq+3)*EMB];
    #pragma unroll
    for (int t=0;t<4;t++){
      float4 zv = ldsz[wslot][t][kq];
      accv[t] = fmaf(zv.x, w0, accv[t]);
      accv[t] = fmaf(zv.y, w1v, accv[t]);
      accv[t] = fmaf(zv.z, w2v, accv[t]);
      accv[t] = fmaf(zv.w, w3, accv[t]);
    }
  }
  #pragma unroll
  for (int t=0;t<4;t++)
    if (i0+t < n) y[(size_t)(i0+t)*EMB + lane] = accv[t];
}

// ---- per-layer stage 3: y = relu(bn1(y)) @ w2m + b2 (in place) ----
__global__ __launch_bounds__(256) void k_l3(float* __restrict__ y,
  const float* __restrict__ st1, const float* __restrict__ g1, const float* __restrict__ be1,
  const float* __restrict__ w2, const float* __restrict__ b2, int n, float invN)
{
  __shared__ float4 ldst[4][4][16];
  int wv = (blockIdx.x*256 + threadIdx.x) >> 6;
  int wslot = (threadIdx.x >> 6) & 3;
  int lane = threadIdx.x & 63;
  int i0 = wv*4;
  float s1 = st1[lane*16], sq1 = st1[(64+lane)*16];
  float g1l = g1[lane], be1l = be1[lane];
  #pragma unroll
  for (int t=0;t<4;t++){
    int i = i0 + t;
    int ii = (i < n) ? i : 0;
    float yv = y[(size_t)ii*EMB + lane];
    ((float*)&ldst[wslot][t])[lane] = bnrelu(yv, s1, sq1, g1l, be1l, invN);
  }
  __syncthreads();
  float b2l = b2[lane];
  float accv[4];
  #pragma unroll
  for (int t=0;t<4;t++) accv[t] = b2l;
  const float* wcol = w2 + lane;
  #pragma unroll 1
  for (int kq=0; kq<16; kq++){
    float w0 = wcol[(4*kq+0)*EMB];
    float w1v = wcol[(4*kq+1)*EMB];
    float w2v = wcol[(4*kq+2)*EMB];
    float w3 = wcol[(4*kq+3)*EMB];
    #pragma unroll
    for (int t=0;t<4;t++){
      float4 tv = ldst[wslot][t][kq];
      accv[t] = fmaf(tv.x, w0, accv[t]);
      accv[t] = fmaf(tv.y, w1v, accv[t]);
      accv[t] = fmaf(tv.z, w2v, accv[t]);
      accv[t] = fmaf(tv.w, w3, accv[t]);
    }
  }
  #pragma unroll
  for (int t=0;t<4;t++)
    if (i0+t < n) y[(size_t)(i0+t)*EMB + lane] = accv[t];
}

// ---- per-channel sum/sumsq -> padded atomics into st (st pre-zeroed) ----
__global__ __launch_bounds__(256) void k_stats(const float* __restrict__ y,
    float* __restrict__ st, int n)
{
  __shared__ float ls[128];
  int lane = threadIdx.x & 63;
  int wid  = threadIdx.x >> 6;
  int gw = blockIdx.x*4 + wid;
  int nw = gridDim.x*4;
  float s=0.f, q=0.f;
  for (int i=gw; i<n; i+=nw){
    float v = y[(size_t)i*EMB + lane];
    s += v; q = fmaf(v,v,q);
  }
  if (threadIdx.x < 128) ls[threadIdx.x] = 0.f;
  __syncthreads();
  atomicAdd(&ls[lane], s); atomicAdd(&ls[64+lane], q);
  __syncthreads();
  if (threadIdx.x < 128) atomicAdd(&st[threadIdx.x*16], ls[threadIdx.x]);
}

// ---- final: h4 = h3 + relu(bn2(y)); out = h4 . wp + bp ----
__global__ __launch_bounds__(64) void k_out(
  const float* __restrict__ h, const float* __restrict__ y,
  const float* __restrict__ st2, const float* __restrict__ g2, const float* __restrict__ be2,
  const float* __restrict__ wp, const float* __restrict__ bp,
  float* __restrict__ out, int n, float invN)
{
  int i = blockIdx.x*64 + threadIdx.x; if (i>=n) return;
  const float* hr = h + (size_t)i*EMB;
  const float* yr = y + (size_t)i*EMB;
  float acc = 0.f;
  #pragma unroll
  for (int q=0;q<16;q++){
    int c0=q*4;
    float4 hv = *(const float4*)(hr+c0);
    float4 yv = *(const float4*)(yr+c0);
    float f0 = hv.x + bnrelu(yv.x, st2[(c0+0)*16], st2[(64+c0+0)*16], g2[c0+0], be2[c0+0], invN);
    float f1 = hv.y + bnrelu(yv.y, st2[(c0+1)*16], st2[(64+c0+1)*16], g2[c0+1], be2[c0+1], invN);
    float f2 = hv.z + bnrelu(yv.z, st2[(c0+2)*16], st2[(64+c0+2)*16], g2[c0+2], be2[c0+2], invN);
    float f3 = hv.w + bnrelu(yv.w, st2[(c0+3)*16], st2[(64+c0+3)*16], g2[c0+3], be2[c0+3], invN);
    acc = fmaf(f0, wp[c0+0], acc);
    acc = fmaf(f1, wp[c0+1], acc);
    acc = fmaf(f2, wp[c0+2], acc);
    acc = fmaf(f3, wp[c0+3], acc);
  }
  out[i] = acc + bp[0];
}

extern "C" void kernel_launch(void* const* d_in, const int* in_sizes, int n_in,
                              void* d_out, int out_size, void* d_ws, size_t ws_size,
                              hipStream_t stream)
{
  const float* x        = (const float*)d_in[0];
  const int*   ei       = (const int*)d_in[1];
  const float* ea       = (const float*)d_in[2];
  const float* lin_in_w = (const float*)d_in[3];
  const float* lin_in_b = (const float*)d_in[4];
  const float* ee_w1    = (const float*)d_in[5];
  const float* ee_b1    = (const float*)d_in[6];
  const float* ee_g1    = (const float*)d_in[7];
  const float* ee_be1   = (const float*)d_in[8];
  const float* ee_w2    = (const float*)d_in[9];
  const float* ee_b2    = (const float*)d_in[10];
  const float* mlp_w1   = (const float*)d_in[11];
  const float* mlp_b1   = (const float*)d_in[12];
  const float* mlp_g1   = (const float*)d_in[13];
  const float* mlp_be1  = (const float*)d_in[14];
  const float* mlp_w2   = (const float*)d_in[15];
  const float* mlp_b2   = (const float*)d_in[16];
  const float* mlp_g2   = (const float*)d_in[17];
  const float* mlp_be2  = (const float*)d_in[18];
  const float* pred_w   = (const float*)d_in[19];
  const float* pred_b   = (const float*)d_in[20];

  int n = in_sizes[0] / INDIM;
  int E = in_sizes[1] / 2;
  const int* srcp = ei;
  const int* dstp = ei + E;

  char* w = (char*)d_ws;
  auto al = [](size_t o){ return (o + 255) & ~(size_t)255; };
  size_t o = 0;
  int*   deg = (int*)(w + o);  o += (size_t)n*4;  o = al(o);
  float* est = (float*)(w + o); o += 144*4;  o = al(o);
  float* nst = (float*)(w + o); o += (size_t)NL*2*2048*4;   // per layer: st1[2048], st2[2048] (16-padded)
  size_t zero_bytes = o;
  o = al(o); int* rs   = (int*)(w + o);   o += (size_t)(n+1)*4;
  o = al(o); int* bsum = (int*)(w + o);   o += 256*4;
  o = al(o); int* boff = (int*)(w + o);   o += 256*4;
  o = al(o); float4* rec = (float4*)(w + o); o += (size_t)E*16;
  o = al(o); float* acb = (float*)(w + o); o += (size_t)NL*256*4;
  o = al(o); float* h   = (float*)(w + o); o += (size_t)n*EMB*4;
  o = al(o); float* hhb = (float*)(w + o); o += (size_t)n*EMB*4;
  o = al(o); float* yb  = (float*)(w + o); o += (size_t)n*EMB*4;

  (void)hipMemsetAsync(d_ws, 0, zero_bytes, stream);

  int nbChunk = (n + 1023)/1024;
  k_pass1<<<512, 256, 0, stream>>>(dstp, ea, E, deg, est);
  k_scanA<<<nbChunk, 256, 0, stream>>>(deg, bsum, n);
  k_scanB<<<1, 64, 0, stream>>>(bsum, boff, rs, nbChunk, n);
  k_scanC<<<nbChunk, 256, 0, stream>>>(deg, boff, rs, n);
  k_scatter<<<1024, 256, 0, stream>>>(srcp, dstp, ea, E, deg /*cur*/, rec);
  k_prec<<<1, 256, 0, stream>>>(est, ee_w1, ee_b1, ee_g1, ee_be1, acb, 1.f/(float)E);

  int nb_h0 = ((n + 7)/8 + 3)/4;        // 8 nodes/wave, 4 waves/block
  int nb_l  = (n + 15)/16;              // 4 nodes/wave, 4 waves/block
  float invN = 1.f/(float)n;
  k_h0<<<nb_h0, 256, 0, stream>>>(x, lin_in_w, lin_in_b, h, n);

  for (int l=0; l<NL; l++){
    float* st1 = nst + (size_t)l*4096;
    float* st2 = st1 + 2048;
    const float* st2prev = (l>0) ? (nst + (size_t)(l-1)*4096 + 2048) : nst;
    const float* g2p  = (l>0) ? (mlp_g2  + (size_t)(l-1)*64) : mlp_g2;
    const float* be2p = (l>0) ? (mlp_be2 + (size_t)(l-1)*64) : mlp_be2;
    k_l1<<<nb_l, 256, 0, stream>>>(h, hhb, yb, rs, rec,
        acb + (size_t)l*256, ee_w2 + (size_t)l*4096, ee_b2 + (size_t)l*64,
        st2prev, g2p, be2p, n, (l>0)?1:0, invN);
    k_l2<<<nb_l, 256, 0, stream>>>(hhb, rs, (const float*)rec,
        mlp_w1 + (size_t)l*4096, mlp_b1 + (size_t)l*64, yb, n);
    k_stats<<<256, 256, 0, stream>>>(yb, st1, n);
    k_l3<<<nb_l, 256, 0, stream>>>(yb, st1,
        mlp_g1 + (size_t)l*64, mlp_be1 + (size_t)l*64,
        mlp_w2 + (size_t)l*4096, mlp_b2 + (size_t)l*64, n, invN);
    k_stats<<<256, 256, 0, stream>>>(yb, st2, n);
  }
  k_out<<<(n+63)/64, 64, 0, stream>>>(h, yb,
      nst + (size_t)(NL-1)*4096 + 2048, mlp_g2 + (size_t)(NL-1)*64, mlp_be2 + (size_t)(NL-1)*64,
      pred_w, pred_b, (float*)d_out, n, invN);
}

// Round 11
// 961.405 us; speedup vs baseline: 2.9118x; 1.0407x over previous
//
#include <hip/hip_runtime.h>

#define EMB 64
#define INDIM 140
#define NL 4
#define EPS 1e-5f

// padded stats: value v lives at st[v*16] (one 64B line per value)
__device__ __forceinline__ float bnrelu(float v, float sum, float sq, float g, float be, float invN){
  float mu  = sum*invN;
  float var = fmaf(-mu, mu, sq*invN);
  float sc  = g * rsqrtf(var + EPS);
  return fmaxf(fmaf(v - mu, sc, be), 0.f);
}

// ---- fused: deg histogram + edge_attr moments ----
__global__ __launch_bounds__(256) void k_pass1(const int* __restrict__ dst,
    const float* __restrict__ ea, int E, int* __restrict__ deg, float* __restrict__ est)
{
  __shared__ float ls[9];
  if (threadIdx.x < 9) ls[threadIdx.x] = 0.f;
  __syncthreads();
  int tid = blockIdx.x*blockDim.x + threadIdx.x;
  int stride = gridDim.x*blockDim.x;
  float a0=0,a1=0,a2=0,p00=0,p11=0,p22=0,p01=0,p02=0,p12=0;
  for (int e=tid;e<E;e+=stride){
    atomicAdd(&deg[dst[e]],1);
    float d0=ea[3*e+0], d1=ea[3*e+1], d2=ea[3*e+2];
    a0+=d0;a1+=d1;a2+=d2;
    p00=fmaf(d0,d0,p00); p11=fmaf(d1,d1,p11); p22=fmaf(d2,d2,p22);
    p01=fmaf(d0,d1,p01); p02=fmaf(d0,d2,p02); p12=fmaf(d1,d2,p12);
  }
  #pragma unroll
  for (int off=32; off>0; off>>=1){
    a0+=__shfl_down(a0,off); a1+=__shfl_down(a1,off); a2+=__shfl_down(a2,off);
    p00+=__shfl_down(p00,off); p11+=__shfl_down(p11,off); p22+=__shfl_down(p22,off);
    p01+=__shfl_down(p01,off); p02+=__shfl_down(p02,off); p12+=__shfl_down(p12,off);
  }
  if ((threadIdx.x & 63)==0){
    atomicAdd(&ls[0],a0); atomicAdd(&ls[1],a1); atomicAdd(&ls[2],a2);
    atomicAdd(&ls[3],p00); atomicAdd(&ls[4],p11); atomicAdd(&ls[5],p22);
    atomicAdd(&ls[6],p01); atomicAdd(&ls[7],p02); atomicAdd(&ls[8],p12);
  }
  __syncthreads();
  if (threadIdx.x < 9) atomicAdd(&est[threadIdx.x*16], ls[threadIdx.x]);
}

// ---- hierarchical scan ----
__global__ __launch_bounds__(256) void k_scanA(const int* __restrict__ deg,
    int* __restrict__ bsum, int n)
{
  int b = blockIdx.x, t = threadIdx.x;
  int i0 = b*1024 + t*4;
  int s = 0;
  if (i0+3 < n){ int4 v = *(const int4*)(deg+i0); s = v.x+v.y+v.z+v.w; }
  else { for (int j=0;j<4;j++){ int i=i0+j; if (i<n) s += deg[i]; } }
  #pragma unroll
  for (int off=32;off>0;off>>=1) s += __shfl_down(s, off);
  __shared__ int ws[4];
  if ((t&63)==0) ws[t>>6] = s;
  __syncthreads();
  if (t==0) bsum[b] = ws[0]+ws[1]+ws[2]+ws[3];
}

__global__ __launch_bounds__(64) void k_scanB(const int* __restrict__ bsum,
    int* __restrict__ boff, int* __restrict__ rs, int nb, int n)
{
  int t = threadIdx.x;
  int carry = 0;
  for (int base=0; base<nb; base+=64){
    int idx = base + t;
    int v = (idx<nb)? bsum[idx] : 0;
    int x = v;
    #pragma unroll
    for (int off=1;off<64;off<<=1){ int u = __shfl_up(x, off); if (t>=off) x += u; }
    if (idx<nb) boff[idx] = carry + x - v;
    int tot = __shfl(x, 63);
    carry += tot;
  }
  if (t==0) rs[n] = carry;
}

__global__ __launch_bounds__(256) void k_scanC(int* __restrict__ deg,
    const int* __restrict__ boff, int* __restrict__ rs, int n)
{
  int b = blockIdx.x, t = threadIdx.x;
  int i0 = b*1024 + t*4;
  int a=0,c=0,d=0,e=0;
  if (i0+3 < n){ int4 v = *(const int4*)(deg+i0); a=v.x;c=v.y;d=v.z;e=v.w; }
  else { if(i0<n)a=deg[i0]; if(i0+1<n)c=deg[i0+1]; if(i0+2<n)d=deg[i0+2]; if(i0+3<n)e=deg[i0+3]; }
  int s4 = a+c+d+e;
  int x = s4;
  int lane = t & 63;
  #pragma unroll
  for (int off=1;off<64;off<<=1){ int u = __shfl_up(x, off); if (lane>=off) x += u; }
  int wexcl = x - s4;
  __shared__ int ws[4];
  if (lane==63) ws[t>>6] = x;
  __syncthreads();
  int base = boff[b];
  int wid = t>>6;
  for (int j=0;j<wid;j++) base += ws[j];
  int p = base + wexcl;
  int r0=p, r1=p+a, r2=p+a+c, r3=p+a+c+d;
  if (i0+3 < n){
    *(int4*)(rs+i0)  = make_int4(r0,r1,r2,r3);
    *(int4*)(deg+i0) = make_int4(r0,r1,r2,r3);
  } else {
    if(i0<n){rs[i0]=r0;deg[i0]=r0;} if(i0+1<n){rs[i0+1]=r1;deg[i0+1]=r1;}
    if(i0+2<n){rs[i0+2]=r2;deg[i0+2]=r2;} if(i0+3<n){rs[i0+3]=r3;deg[i0+3]=r3;}
  }
}

// ---- scatter edges into dst-sorted 16B records {d0,d1,d2,(float)src} ----
__global__ __launch_bounds__(256) void k_scatter(const int* __restrict__ src,
    const int* __restrict__ dst, const float* __restrict__ ea, int E,
    int* __restrict__ cur, float4* __restrict__ rec)
{
  int tid = blockIdx.x*blockDim.x + threadIdx.x;
  int stride = gridDim.x*blockDim.x;
  for (int e=tid;e<E;e+=stride){
    int d = dst[e];
    int p = atomicAdd(&cur[d], 1);
    rec[p] = make_float4(ea[3*e+0], ea[3*e+1], ea[3*e+2], (float)src[e]);
  }
}

// ---- fold edge-BN into affine A,c per layer/channel ----
__global__ __launch_bounds__(256) void k_prec(const float* __restrict__ est,
  const float* __restrict__ w1, const float* __restrict__ b1,
  const float* __restrict__ g1, const float* __restrict__ be1,
  float* __restrict__ ac, float invE)
{
  int t = threadIdx.x; int l = t>>6, c = t&63;
  float m0 = est[0]*invE, m1 = est[16]*invE, m2 = est[32]*invE;
  float c00 = est[48]*invE - m0*m0, c11 = est[64]*invE - m1*m1, c22 = est[80]*invE - m2*m2;
  float c01 = est[96]*invE - m0*m1, c02 = est[112]*invE - m0*m2, c12 = est[128]*invE - m1*m2;
  float w0 = w1[(l*3+0)*64+c], w1_ = w1[(l*3+1)*64+c], w2_ = w1[(l*3+2)*64+c];
  float b = b1[l*64+c], g = g1[l*64+c], be = be1[l*64+c];
  float mu = m0*w0 + m1*w1_ + m2*w2_ + b;
  float var = w0*w0*c00 + w1_*w1_*c11 + w2_*w2_*c22
            + 2.f*(w0*w1_*c01 + w0*w2_*c02 + w1_*w2_*c12);
  float sc = g * rsqrtf(var + EPS);
  float* o = ac + l*256 + c*4;
  o[0] = w0*sc; o[1] = w1_*sc; o[2] = w2_*sc; o[3] = (b - mu)*sc + be;
}

// ---- h0 = x @ lin_in_w + b : 8 nodes/wave, x rows staged in LDS ----
__global__ __launch_bounds__(256) void k_h0(const float* __restrict__ x,
  const float* __restrict__ w, const float* __restrict__ b, float* __restrict__ h, int n)
{
  __shared__ float4 s_x[4][280];            // 4 waves x (8 rows x 35 float4)
  int wv = (blockIdx.x*256 + threadIdx.x) >> 6;
  int wslot = (threadIdx.x >> 6) & 3;
  int lane = threadIdx.x & 63;
  int i0 = wv*8;
  int m = n - i0; if (m > 8) m = 8; if (m < 0) m = 0;
  int limit = m*35;
  const float4* xp4 = (const float4*)(x + (size_t)i0*INDIM);
  #pragma unroll
  for (int j=0;j<5;j++){
    int idx = j*64 + lane;
    if (idx < limit) s_x[wslot][idx] = xp4[idx];
  }
  __syncthreads();
  float acc[8];
  float bl = b[lane];
  #pragma unroll
  for (int t=0;t<8;t++) acc[t] = bl;
  const float* wcol = w + lane;
  #pragma unroll 1
  for (int kq=0; kq<35; kq++){
    float w0 = wcol[(4*kq+0)*EMB];
    float w1 = wcol[(4*kq+1)*EMB];
    float w2 = wcol[(4*kq+2)*EMB];
    float w3 = wcol[(4*kq+3)*EMB];
    #pragma unroll
    for (int t=0;t<8;t++){
      float4 xv = s_x[wslot][t*35 + kq];
      acc[t] = fmaf(xv.x, w0, acc[t]);
      acc[t] = fmaf(xv.y, w1, acc[t]);
      acc[t] = fmaf(xv.z, w2, acc[t]);
      acc[t] = fmaf(xv.w, w3, acc[t]);
    }
  }
  #pragma unroll
  for (int t=0;t<8;t++)
    if (t < m) h[(size_t)(i0+t)*EMB + lane] = acc[t];
}

// ---- fused per-layer stage 1: h update + edge encoder + r@w2 -> hh ----
__global__ __launch_bounds__(256) void k_l1(
  float* __restrict__ h, float* __restrict__ hh, const float* __restrict__ yprev,
  const int* __restrict__ rs, const float4* __restrict__ rec,
  const float* __restrict__ ac, const float* __restrict__ w2, const float* __restrict__ b2,
  const float* __restrict__ st2, const float* __restrict__ g2, const float* __restrict__ be2,
  int n, int update, float invN)
{
  __shared__ float4 ldsr[4][4][16];         // [wave][node][16 float4]
  int wv = (blockIdx.x*256 + threadIdx.x) >> 6;
  int wslot = (threadIdx.x >> 6) & 3;
  int lane = threadIdx.x & 63;
  int i0 = wv*4;
  float4 a = ((const float4*)ac)[lane];
  float b2l = b2[lane];
  float accv[4];
  #pragma unroll
  for (int t=0;t<4;t++){
    int i = i0 + t;
    bool act = (i < n);
    int ii = act ? i : 0;
    int e0 = rs[ii], e1 = rs[ii+1];         // vector loads (per-call-varying data)
    float racc = 0.f;
    int e = e0;
    for (; e+8<=e1; e+=8){                  // 8-deep: more loads in flight
      float4 d0 = rec[e],   d1 = rec[e+1], d2 = rec[e+2], d3 = rec[e+3];
      float4 d4 = rec[e+4], d5 = rec[e+5], d6 = rec[e+6], d7 = rec[e+7];
      racc += fmaxf(fmaf(d0.x,a.x,fmaf(d0.y,a.y,fmaf(d0.z,a.z,a.w))),0.f);
      racc += fmaxf(fmaf(d1.x,a.x,fmaf(d1.y,a.y,fmaf(d1.z,a.z,a.w))),0.f);
      racc += fmaxf(fmaf(d2.x,a.x,fmaf(d2.y,a.y,fmaf(d2.z,a.z,a.w))),0.f);
      racc += fmaxf(fmaf(d3.x,a.x,fmaf(d3.y,a.y,fmaf(d3.z,a.z,a.w))),0.f);
      racc += fmaxf(fmaf(d4.x,a.x,fmaf(d4.y,a.y,fmaf(d4.z,a.z,a.w))),0.f);
      racc += fmaxf(fmaf(d5.x,a.x,fmaf(d5.y,a.y,fmaf(d5.z,a.z,a.w))),0.f);
      racc += fmaxf(fmaf(d6.x,a.x,fmaf(d6.y,a.y,fmaf(d6.z,a.z,a.w))),0.f);
      racc += fmaxf(fmaf(d7.x,a.x,fmaf(d7.y,a.y,fmaf(d7.z,a.z,a.w))),0.f);
    }
    for (; e<e1; e++){
      float4 d0 = rec[e];
      racc += fmaxf(fmaf(d0.x,a.x,fmaf(d0.y,a.y,fmaf(d0.z,a.z,a.w))),0.f);
    }
    ((float*)&ldsr[wslot][t])[lane] = racc;
    float hv = h[(size_t)ii*EMB + lane];
    if (update){
      float yv = yprev[(size_t)ii*EMB + lane];
      hv += bnrelu(yv, st2[lane*16], st2[(64+lane)*16], g2[lane], be2[lane], invN);
      if (act) h[(size_t)i*EMB + lane] = hv;
    }
    float degf = (float)(e1 - e0);
    accv[t] = fmaf(degf, b2l, hv);
  }
  __syncthreads();
  const float* wcol = w2 + lane;
  #pragma unroll 1
  for (int kq=0; kq<16; kq++){
    float w0 = wcol[(4*kq+0)*EMB];
    float w1v = wcol[(4*kq+1)*EMB];
    float w2v = wcol[(4*kq+2)*EMB];
    float w3 = wcol[(4*kq+3)*EMB];
    #pragma unroll
    for (int t=0;t<4;t++){
      float4 rv = ldsr[wslot][t][kq];
      accv[t] = fmaf(rv.x, w0, accv[t]);
      accv[t] = fmaf(rv.y, w1v, accv[t]);
      accv[t] = fmaf(rv.z, w2v, accv[t]);
      accv[t] = fmaf(rv.w, w3, accv[t]);
    }
  }
  #pragma unroll
  for (int t=0;t<4;t++)
    if (i0+t < n) hh[(size_t)(i0+t)*EMB + lane] = accv[t];
}

// ---- fused per-layer stage 2: gather(8-deep) + (hh+msg)@w1 + b1 -> y, + partial stats ----
__global__ __launch_bounds__(256) void k_l2(
  const float* __restrict__ hh, const int* __restrict__ rs, const float* __restrict__ recw,
  const float* __restrict__ w1, const float* __restrict__ b1,
  float* __restrict__ y, float* __restrict__ pst, int n)
{
  __shared__ float4 ldsz[4][4][16];
  __shared__ float ls[128];
  int wv = (blockIdx.x*256 + threadIdx.x) >> 6;
  int wslot = (threadIdx.x >> 6) & 3;
  int lane = threadIdx.x & 63;
  int i0 = wv*4;
  if (threadIdx.x < 128) ls[threadIdx.x] = 0.f;
  #pragma unroll
  for (int t=0;t<4;t++){
    int i = i0 + t;
    bool act = (i < n);
    int ii = act ? i : 0;
    int e0 = rs[ii], e1 = rs[ii+1];
    float zc = hh[(size_t)ii*EMB + lane];
    int e = e0;
    for (; e+8<=e1; e+=8){                  // 8 outstanding row-gathers
      int s0 = (int)recw[4*(e+0)+3];
      int s1 = (int)recw[4*(e+1)+3];
      int s2 = (int)recw[4*(e+2)+3];
      int s3 = (int)recw[4*(e+3)+3];
      int s4 = (int)recw[4*(e+4)+3];
      int s5 = (int)recw[4*(e+5)+3];
      int s6 = (int)recw[4*(e+6)+3];
      int s7 = (int)recw[4*(e+7)+3];
      float g0 = hh[(size_t)s0*EMB + lane];
      float g1 = hh[(size_t)s1*EMB + lane];
      float g2 = hh[(size_t)s2*EMB + lane];
      float g3 = hh[(size_t)s3*EMB + lane];
      float g4 = hh[(size_t)s4*EMB + lane];
      float g5 = hh[(size_t)s5*EMB + lane];
      float g6 = hh[(size_t)s6*EMB + lane];
      float g7 = hh[(size_t)s7*EMB + lane];
      zc += ((g0+g1)+(g2+g3)) + ((g4+g5)+(g6+g7));
    }
    for (; e<e1; e++){
      int s0 = (int)recw[4*e+3];
      zc += hh[(size_t)s0*EMB + lane];
    }
    ((float*)&ldsz[wslot][t])[lane] = zc;
  }
  __syncthreads();
  float b1l = b1[lane];
  float accv[4];
  #pragma unroll
  for (int t=0;t<4;t++) accv[t] = b1l;
  const float* wcol = w1 + lane;
  #pragma unroll 1
  for (int kq=0; kq<16; kq++){
    float w0 = wcol[(4*kq+0)*EMB];
    float w1v = wcol[(4*kq+1)*EMB];
    float w2v = wcol[(4*kq+2)*EMB];
    float w3 = wcol[(4*kq+3)*EMB];
    #pragma unroll
    for (int t=0;t<4;t++){
      float4 zv = ldsz[wslot][t][kq];
      accv[t] = fmaf(zv.x, w0, accv[t]);
      accv[t] = fmaf(zv.y, w1v, accv[t]);
      accv[t] = fmaf(zv.z, w2v, accv[t]);
      accv[t] = fmaf(zv.w, w3, accv[t]);
    }
  }
  float ssum = 0.f, ssq = 0.f;
  #pragma unroll
  for (int t=0;t<4;t++){
    if (i0+t < n){
      y[(size_t)(i0+t)*EMB + lane] = accv[t];
      ssum += accv[t];
      ssq = fmaf(accv[t], accv[t], ssq);
    }
  }
  atomicAdd(&ls[lane], ssum); atomicAdd(&ls[64+lane], ssq);
  __syncthreads();
  if (threadIdx.x < 128) pst[(size_t)blockIdx.x*128 + threadIdx.x] = ls[threadIdx.x];
}

// ---- per-layer stage 3: y = relu(bn1(y)) @ w2m + b2 (in place) + partial stats ----
__global__ __launch_bounds__(256) void k_l3(float* __restrict__ y,
  const float* __restrict__ st1, const float* __restrict__ g1, const float* __restrict__ be1,
  const float* __restrict__ w2, const float* __restrict__ b2,
  float* __restrict__ pst, int n, float invN)
{
  __shared__ float4 ldst[4][4][16];
  __shared__ float ls[128];
  int wv = (blockIdx.x*256 + threadIdx.x) >> 6;
  int wslot = (threadIdx.x >> 6) & 3;
  int lane = threadIdx.x & 63;
  int i0 = wv*4;
  if (threadIdx.x < 128) ls[threadIdx.x] = 0.f;
  float s1 = st1[lane*16], sq1 = st1[(64+lane)*16];
  float g1l = g1[lane], be1l = be1[lane];
  #pragma unroll
  for (int t=0;t<4;t++){
    int i = i0 + t;
    int ii = (i < n) ? i : 0;
    float yv = y[(size_t)ii*EMB + lane];
    ((float*)&ldst[wslot][t])[lane] = bnrelu(yv, s1, sq1, g1l, be1l, invN);
  }
  __syncthreads();
  float b2l = b2[lane];
  float accv[4];
  #pragma unroll
  for (int t=0;t<4;t++) accv[t] = b2l;
  const float* wcol = w2 + lane;
  #pragma unroll 1
  for (int kq=0; kq<16; kq++){
    float w0 = wcol[(4*kq+0)*EMB];
    float w1v = wcol[(4*kq+1)*EMB];
    float w2v = wcol[(4*kq+2)*EMB];
    float w3 = wcol[(4*kq+3)*EMB];
    #pragma unroll
    for (int t=0;t<4;t++){
      float4 tv = ldst[wslot][t][kq];
      accv[t] = fmaf(tv.x, w0, accv[t]);
      accv[t] = fmaf(tv.y, w1v, accv[t]);
      accv[t] = fmaf(tv.z, w2v, accv[t]);
      accv[t] = fmaf(tv.w, w3, accv[t]);
    }
  }
  float ssum = 0.f, ssq = 0.f;
  #pragma unroll
  for (int t=0;t<4;t++){
    if (i0+t < n){
      y[(size_t)(i0+t)*EMB + lane] = accv[t];
      ssum += accv[t];
      ssq = fmaf(accv[t], accv[t], ssq);
    }
  }
  atomicAdd(&ls[lane], ssum); atomicAdd(&ls[64+lane], ssq);
  __syncthreads();
  if (threadIdx.x < 128) pst[(size_t)blockIdx.x*128 + threadIdx.x] = ls[threadIdx.x];
}

// ---- reduce per-block partials: one block per channel-slot (0..127) ----
__global__ __launch_bounds__(256) void k_red(const float* __restrict__ pst,
    float* __restrict__ st, int nb)
{
  int ch = blockIdx.x;
  float s = 0.f;
  for (int i=threadIdx.x; i<nb; i+=256) s += pst[(size_t)i*128 + ch];
  #pragma unroll
  for (int off=32; off>0; off>>=1) s += __shfl_down(s, off);
  __shared__ float ws[4];
  if ((threadIdx.x&63)==0) ws[threadIdx.x>>6] = s;
  __syncthreads();
  if (threadIdx.x==0) st[ch*16] = ws[0]+ws[1]+ws[2]+ws[3];
}

// ---- final: h4 = h3 + relu(bn2(y)); out = h4 . wp + bp ----
__global__ __launch_bounds__(64) void k_out(
  const float* __restrict__ h, const float* __restrict__ y,
  const float* __restrict__ st2, const float* __restrict__ g2, const float* __restrict__ be2,
  const float* __restrict__ wp, const float* __restrict__ bp,
  float* __restrict__ out, int n, float invN)
{
  int i = blockIdx.x*64 + threadIdx.x; if (i>=n) return;
  const float* hr = h + (size_t)i*EMB;
  const float* yr = y + (size_t)i*EMB;
  float acc = 0.f;
  #pragma unroll
  for (int q=0;q<16;q++){
    int c0=q*4;
    float4 hv = *(const float4*)(hr+c0);
    float4 yv = *(const float4*)(yr+c0);
    float f0 = hv.x + bnrelu(yv.x, st2[(c0+0)*16], st2[(64+c0+0)*16], g2[c0+0], be2[c0+0], invN);
    float f1 = hv.y + bnrelu(yv.y, st2[(c0+1)*16], st2[(64+c0+1)*16], g2[c0+1], be2[c0+1], invN);
    float f2 = hv.z + bnrelu(yv.z, st2[(c0+2)*16], st2[(64+c0+2)*16], g2[c0+2], be2[c0+2], invN);
    float f3 = hv.w + bnrelu(yv.w, st2[(c0+3)*16], st2[(64+c0+3)*16], g2[c0+3], be2[c0+3], invN);
    acc = fmaf(f0, wp[c0+0], acc);
    acc = fmaf(f1, wp[c0+1], acc);
    acc = fmaf(f2, wp[c0+2], acc);
    acc = fmaf(f3, wp[c0+3], acc);
  }
  out[i] = acc + bp[0];
}

extern "C" void kernel_launch(void* const* d_in, const int* in_sizes, int n_in,
                              void* d_out, int out_size, void* d_ws, size_t ws_size,
                              hipStream_t stream)
{
  const float* x        = (const float*)d_in[0];
  const int*   ei       = (const int*)d_in[1];
  const float* ea       = (const float*)d_in[2];
  const float* lin_in_w = (const float*)d_in[3];
  const float* lin_in_b = (const float*)d_in[4];
  const float* ee_w1    = (const float*)d_in[5];
  const float* ee_b1    = (const float*)d_in[6];
  const float* ee_g1    = (const float*)d_in[7];
  const float* ee_be1   = (const float*)d_in[8];
  const float* ee_w2    = (const float*)d_in[9];
  const float* ee_b2    = (const float*)d_in[10];
  const float* mlp_w1   = (const float*)d_in[11];
  const float* mlp_b1   = (const float*)d_in[12];
  const float* mlp_g1   = (const float*)d_in[13];
  const float* mlp_be1  = (const float*)d_in[14];
  const float* mlp_w2   = (const float*)d_in[15];
  const float* mlp_b2   = (const float*)d_in[16];
  const float* mlp_g2   = (const float*)d_in[17];
  const float* mlp_be2  = (const float*)d_in[18];
  const float* pred_w   = (const float*)d_in[19];
  const float* pred_b   = (const float*)d_in[20];

  int n = in_sizes[0] / INDIM;
  int E = in_sizes[1] / 2;
  const int* srcp = ei;
  const int* dstp = ei + E;

  char* w = (char*)d_ws;
  auto al = [](size_t o){ return (o + 255) & ~(size_t)255; };
  size_t o = 0;
  int*   deg = (int*)(w + o);  o += (size_t)n*4;  o = al(o);
  float* est = (float*)(w + o); o += 144*4;  o = al(o);
  size_t zero_bytes = o;
  o = al(o); float* nst = (float*)(w + o); o += (size_t)NL*2*2048*4;  // st1/st2 per layer (16-padded)
  o = al(o); int* rs   = (int*)(w + o);   o += (size_t)(n+1)*4;
  o = al(o); int* bsum = (int*)(w + o);   o += 256*4;
  o = al(o); int* boff = (int*)(w + o);   o += 256*4;
  o = al(o); float4* rec = (float4*)(w + o); o += (size_t)E*16;
  o = al(o); float* acb = (float*)(w + o); o += (size_t)NL*256*4;
  o = al(o); float* h   = (float*)(w + o); o += (size_t)n*EMB*4;
  o = al(o); float* hhb = (float*)(w + o); o += (size_t)n*EMB*4;
  o = al(o); float* yb  = (float*)(w + o); o += (size_t)n*EMB*4;
  o = al(o); float* pst = (float*)(w + o); o += (size_t)4096*128*4;

  (void)hipMemsetAsync(d_ws, 0, zero_bytes, stream);

  int nbChunk = (n + 1023)/1024;
  k_pass1<<<512, 256, 0, stream>>>(dstp, ea, E, deg, est);
  k_scanA<<<nbChunk, 256, 0, stream>>>(deg, bsum, n);
  k_scanB<<<1, 64, 0, stream>>>(bsum, boff, rs, nbChunk, n);
  k_scanC<<<nbChunk, 256, 0, stream>>>(deg, boff, rs, n);
  k_scatter<<<1024, 256, 0, stream>>>(srcp, dstp, ea, E, deg /*cur*/, rec);
  k_prec<<<1, 256, 0, stream>>>(est, ee_w1, ee_b1, ee_g1, ee_be1, acb, 1.f/(float)E);

  int nb_h0 = ((n + 7)/8 + 3)/4;        // 8 nodes/wave, 4 waves/block
  int nb_l  = (n + 15)/16;              // 4 nodes/wave, 4 waves/block
  float invN = 1.f/(float)n;
  k_h0<<<nb_h0, 256, 0, stream>>>(x, lin_in_w, lin_in_b, h, n);

  for (int l=0; l<NL; l++){
    float* st1 = nst + (size_t)l*4096;
    float* st2 = st1 + 2048;
    const float* st2prev = (l>0) ? (nst + (size_t)(l-1)*4096 + 2048) : nst;
    const float* g2p  = (l>0) ? (mlp_g2  + (size_t)(l-1)*64) : mlp_g2;
    const float* be2p = (l>0) ? (mlp_be2 + (size_t)(l-1)*64) : mlp_be2;
    k_l1<<<nb_l, 256, 0, stream>>>(h, hhb, yb, rs, rec,
        acb + (size_t)l*256, ee_w2 + (size_t)l*4096, ee_b2 + (size_t)l*64,
        st2prev, g2p, be2p, n, (l>0)?1:0, invN);
    k_l2<<<nb_l, 256, 0, stream>>>(hhb, rs, (const float*)rec,
        mlp_w1 + (size_t)l*4096, mlp_b1 + (size_t)l*64, yb, pst, n);
    k_red<<<128, 256, 0, stream>>>(pst, st1, nb_l);
    k_l3<<<nb_l, 256, 0, stream>>>(yb, st1,
        mlp_g1 + (size_t)l*64, mlp_be1 + (size_t)l*64,
        mlp_w2 + (size_t)l*4096, mlp_b2 + (size_t)l*64, pst, n, invN);
    k_red<<<128, 256, 0, stream>>>(pst, st2, nb_l);
  }
  k_out<<<(n+63)/64, 64, 0, stream>>>(h, yb,
      nst + (size_t)(NL-1)*4096 + 2048, mlp_g2 + (size_t)(NL-1)*64, mlp_be2 + (size_t)(NL-1)*64,
      pred_w, pred_b, (float*)d_out, n, invN);
}

// Round 12
// 816.594 us; speedup vs baseline: 3.4282x; 1.1773x over previous
//
#include <hip/hip_runtime.h>
#include <hip/hip_bf16.h>

#define EMB 64
#define INDIM 140
#define NL 4
#define EPS 1e-5f

__device__ __forceinline__ unsigned short f2bf(float f){
  __hip_bfloat16 b = __float2bfloat16(f);   // round-to-nearest
  return *reinterpret_cast<unsigned short*>(&b);
}
__device__ __forceinline__ float bf2f(unsigned short u){
  __hip_bfloat16 b = *reinterpret_cast<__hip_bfloat16*>(&u);
  return __bfloat162float(b);
}

// padded stats: value v lives at st[v*16] (one 64B line per value)
__device__ __forceinline__ float bnrelu(float v, float sum, float sq, float g, float be, float invN){
  float mu  = sum*invN;
  float var = fmaf(-mu, mu, sq*invN);
  float sc  = g * rsqrtf(var + EPS);
  return fmaxf(fmaf(v - mu, sc, be), 0.f);
}

// ---- fused: deg histogram (saving per-edge rank) + edge_attr moments ----
__global__ __launch_bounds__(256) void k_pass1(const int* __restrict__ dst,
    const float* __restrict__ ea, int E, int* __restrict__ deg,
    int* __restrict__ rank, float* __restrict__ est)
{
  __shared__ float ls[9];
  if (threadIdx.x < 9) ls[threadIdx.x] = 0.f;
  __syncthreads();
  int tid = blockIdx.x*blockDim.x + threadIdx.x;
  int stride = gridDim.x*blockDim.x;
  float a0=0,a1=0,a2=0,p00=0,p11=0,p22=0,p01=0,p02=0,p12=0;
  for (int e=tid;e<E;e+=stride){
    rank[e] = atomicAdd(&deg[dst[e]],1);   // rank within dst bucket (order arbitrary, valid)
    float d0=ea[3*e+0], d1=ea[3*e+1], d2=ea[3*e+2];
    a0+=d0;a1+=d1;a2+=d2;
    p00=fmaf(d0,d0,p00); p11=fmaf(d1,d1,p11); p22=fmaf(d2,d2,p22);
    p01=fmaf(d0,d1,p01); p02=fmaf(d0,d2,p02); p12=fmaf(d1,d2,p12);
  }
  #pragma unroll
  for (int off=32; off>0; off>>=1){
    a0+=__shfl_down(a0,off); a1+=__shfl_down(a1,off); a2+=__shfl_down(a2,off);
    p00+=__shfl_down(p00,off); p11+=__shfl_down(p11,off); p22+=__shfl_down(p22,off);
    p01+=__shfl_down(p01,off); p02+=__shfl_down(p02,off); p12+=__shfl_down(p12,off);
  }
  if ((threadIdx.x & 63)==0){
    atomicAdd(&ls[0],a0); atomicAdd(&ls[1],a1); atomicAdd(&ls[2],a2);
    atomicAdd(&ls[3],p00); atomicAdd(&ls[4],p11); atomicAdd(&ls[5],p22);
    atomicAdd(&ls[6],p01); atomicAdd(&ls[7],p02); atomicAdd(&ls[8],p12);
  }
  __syncthreads();
  if (threadIdx.x < 9) atomicAdd(&est[threadIdx.x*16], ls[threadIdx.x]);
}

// ---- hierarchical scan ----
__global__ __launch_bounds__(256) void k_scanA(const int* __restrict__ deg,
    int* __restrict__ bsum, int n)
{
  int b = blockIdx.x, t = threadIdx.x;
  int i0 = b*1024 + t*4;
  int s = 0;
  if (i0+3 < n){ int4 v = *(const int4*)(deg+i0); s = v.x+v.y+v.z+v.w; }
  else { for (int j=0;j<4;j++){ int i=i0+j; if (i<n) s += deg[i]; } }
  #pragma unroll
  for (int off=32;off>0;off>>=1) s += __shfl_down(s, off);
  __shared__ int ws[4];
  if ((t&63)==0) ws[t>>6] = s;
  __syncthreads();
  if (t==0) bsum[b] = ws[0]+ws[1]+ws[2]+ws[3];
}

__global__ __launch_bounds__(64) void k_scanB(const int* __restrict__ bsum,
    int* __restrict__ boff, int* __restrict__ rs, int nb, int n)
{
  int t = threadIdx.x;
  int carry = 0;
  for (int base=0; base<nb; base+=64){
    int idx = base + t;
    int v = (idx<nb)? bsum[idx] : 0;
    int x = v;
    #pragma unroll
    for (int off=1;off<64;off<<=1){ int u = __shfl_up(x, off); if (t>=off) x += u; }
    if (idx<nb) boff[idx] = carry + x - v;
    int tot = __shfl(x, 63);
    carry += tot;
  }
  if (t==0) rs[n] = carry;
}

__global__ __launch_bounds__(256) void k_scanC(int* __restrict__ deg,
    const int* __restrict__ boff, int* __restrict__ rs, int n)
{
  int b = blockIdx.x, t = threadIdx.x;
  int i0 = b*1024 + t*4;
  int a=0,c=0,d=0,e=0;
  if (i0+3 < n){ int4 v = *(const int4*)(deg+i0); a=v.x;c=v.y;d=v.z;e=v.w; }
  else { if(i0<n)a=deg[i0]; if(i0+1<n)c=deg[i0+1]; if(i0+2<n)d=deg[i0+2]; if(i0+3<n)e=deg[i0+3]; }
  int s4 = a+c+d+e;
  int x = s4;
  int lane = t & 63;
  #pragma unroll
  for (int off=1;off<64;off<<=1){ int u = __shfl_up(x, off); if (lane>=off) x += u; }
  int wexcl = x - s4;
  __shared__ int ws[4];
  if (lane==63) ws[t>>6] = x;
  __syncthreads();
  int base = boff[b];
  int wid = t>>6;
  for (int j=0;j<wid;j++) base += ws[j];
  int p = base + wexcl;
  int r0=p, r1=p+a, r2=p+a+c, r3=p+a+c+d;
  if (i0+3 < n){
    *(int4*)(rs+i0)  = make_int4(r0,r1,r2,r3);
  } else {
    if(i0<n)rs[i0]=r0; if(i0+1<n)rs[i0+1]=r1;
    if(i0+2<n)rs[i0+2]=r2; if(i0+3<n)rs[i0+3]=r3;
  }
}

// ---- scatter edges into dst-sorted 16B records; NO atomics (rank precomputed) ----
__global__ __launch_bounds__(256) void k_scatter(const int* __restrict__ src,
    const int* __restrict__ dst, const float* __restrict__ ea, int E,
    const int* __restrict__ rs, const int* __restrict__ rank, float4* __restrict__ rec)
{
  int tid = blockIdx.x*blockDim.x + threadIdx.x;
  int stride = gridDim.x*blockDim.x;
  for (int e=tid;e<E;e+=stride){
    int p = rs[dst[e]] + rank[e];
    rec[p] = make_float4(ea[3*e+0], ea[3*e+1], ea[3*e+2], (float)src[e]);
  }
}

// ---- fold edge-BN into affine A,c per layer/channel ----
__global__ __launch_bounds__(256) void k_prec(const float* __restrict__ est,
  const float* __restrict__ w1, const float* __restrict__ b1,
  const float* __restrict__ g1, const float* __restrict__ be1,
  float* __restrict__ ac, float invE)
{
  int t = threadIdx.x; int l = t>>6, c = t&63;
  float m0 = est[0]*invE, m1 = est[16]*invE, m2 = est[32]*invE;
  float c00 = est[48]*invE - m0*m0, c11 = est[64]*invE - m1*m1, c22 = est[80]*invE - m2*m2;
  float c01 = est[96]*invE - m0*m1, c02 = est[112]*invE - m0*m2, c12 = est[128]*invE - m1*m2;
  float w0 = w1[(l*3+0)*64+c], w1_ = w1[(l*3+1)*64+c], w2_ = w1[(l*3+2)*64+c];
  float b = b1[l*64+c], g = g1[l*64+c], be = be1[l*64+c];
  float mu = m0*w0 + m1*w1_ + m2*w2_ + b;
  float var = w0*w0*c00 + w1_*w1_*c11 + w2_*w2_*c22
            + 2.f*(w0*w1_*c01 + w0*w2_*c02 + w1_*w2_*c12);
  float sc = g * rsqrtf(var + EPS);
  float* o = ac + l*256 + c*4;
  o[0] = w0*sc; o[1] = w1_*sc; o[2] = w2_*sc; o[3] = (b - mu)*sc + be;
}

// ---- h0 = x @ lin_in_w + b : 8 nodes/wave, x rows staged in LDS ----
__global__ __launch_bounds__(256) void k_h0(const float* __restrict__ x,
  const float* __restrict__ w, const float* __restrict__ b, float* __restrict__ h, int n)
{
  __shared__ float4 s_x[4][280];            // 4 waves x (8 rows x 35 float4)
  int wv = (blockIdx.x*256 + threadIdx.x) >> 6;
  int wslot = (threadIdx.x >> 6) & 3;
  int lane = threadIdx.x & 63;
  int i0 = wv*8;
  int m = n - i0; if (m > 8) m = 8; if (m < 0) m = 0;
  int limit = m*35;
  const float4* xp4 = (const float4*)(x + (size_t)i0*INDIM);
  #pragma unroll
  for (int j=0;j<5;j++){
    int idx = j*64 + lane;
    if (idx < limit) s_x[wslot][idx] = xp4[idx];
  }
  __syncthreads();
  float acc[8];
  float bl = b[lane];
  #pragma unroll
  for (int t=0;t<8;t++) acc[t] = bl;
  const float* wcol = w + lane;
  #pragma unroll 2
  for (int kq=0; kq<35; kq++){
    float w0 = wcol[(4*kq+0)*EMB];
    float w1 = wcol[(4*kq+1)*EMB];
    float w2 = wcol[(4*kq+2)*EMB];
    float w3 = wcol[(4*kq+3)*EMB];
    #pragma unroll
    for (int t=0;t<8;t++){
      float4 xv = s_x[wslot][t*35 + kq];
      acc[t] = fmaf(xv.x, w0, acc[t]);
      acc[t] = fmaf(xv.y, w1, acc[t]);
      acc[t] = fmaf(xv.z, w2, acc[t]);
      acc[t] = fmaf(xv.w, w3, acc[t]);
    }
  }
  #pragma unroll
  for (int t=0;t<8;t++)
    if (t < m) h[(size_t)(i0+t)*EMB + lane] = acc[t];
}

// ---- fused per-layer stage 1: h update + edge encoder + r@w2 -> hh(bf16) ----
__global__ __launch_bounds__(256) void k_l1(
  float* __restrict__ h, unsigned short* __restrict__ hh16, const float* __restrict__ yprev,
  const int* __restrict__ rs, const float4* __restrict__ rec,
  const float* __restrict__ ac, const float* __restrict__ w2, const float* __restrict__ b2,
  const float* __restrict__ st2, const float* __restrict__ g2, const float* __restrict__ be2,
  int n, int update, float invN)
{
  __shared__ float4 ldsr[4][4][16];         // [wave][node][16 float4]
  int wv = (blockIdx.x*256 + threadIdx.x) >> 6;
  int wslot = (threadIdx.x >> 6) & 3;
  int lane = threadIdx.x & 63;
  int i0 = wv*4;
  float4 a = ((const float4*)ac)[lane];
  float b2l = b2[lane];
  float s2s = 0.f, s2q = 0.f, g2l = 0.f, be2l = 0.f;
  if (update){ s2s = st2[lane*16]; s2q = st2[(64+lane)*16]; g2l = g2[lane]; be2l = be2[lane]; }
  float accv[4];
  #pragma unroll
  for (int t=0;t<4;t++){
    int i = i0 + t;
    bool act = (i < n);
    int ii = act ? i : 0;
    int e0 = rs[ii], e1 = rs[ii+1];         // vector loads (per-call-varying data)
    // issue h/yprev loads before the long edge loop so they complete under it
    float hv = h[(size_t)ii*EMB + lane];
    if (update){
      float yv = yprev[(size_t)ii*EMB + lane];
      hv += bnrelu(yv, s2s, s2q, g2l, be2l, invN);
      if (act) h[(size_t)i*EMB + lane] = hv;
    }
    float racc = 0.f;
    int e = e0;
    for (; e+8<=e1; e+=8){                  // 8-deep: more loads in flight
      float4 d0 = rec[e],   d1 = rec[e+1], d2 = rec[e+2], d3 = rec[e+3];
      float4 d4 = rec[e+4], d5 = rec[e+5], d6 = rec[e+6], d7 = rec[e+7];
      racc += fmaxf(fmaf(d0.x,a.x,fmaf(d0.y,a.y,fmaf(d0.z,a.z,a.w))),0.f);
      racc += fmaxf(fmaf(d1.x,a.x,fmaf(d1.y,a.y,fmaf(d1.z,a.z,a.w))),0.f);
      racc += fmaxf(fmaf(d2.x,a.x,fmaf(d2.y,a.y,fmaf(d2.z,a.z,a.w))),0.f);
      racc += fmaxf(fmaf(d3.x,a.x,fmaf(d3.y,a.y,fmaf(d3.z,a.z,a.w))),0.f);
      racc += fmaxf(fmaf(d4.x,a.x,fmaf(d4.y,a.y,fmaf(d4.z,a.z,a.w))),0.f);
      racc += fmaxf(fmaf(d5.x,a.x,fmaf(d5.y,a.y,fmaf(d5.z,a.z,a.w))),0.f);
      racc += fmaxf(fmaf(d6.x,a.x,fmaf(d6.y,a.y,fmaf(d6.z,a.z,a.w))),0.f);
      racc += fmaxf(fmaf(d7.x,a.x,fmaf(d7.y,a.y,fmaf(d7.z,a.z,a.w))),0.f);
    }
    for (; e<e1; e++){
      float4 d0 = rec[e];
      racc += fmaxf(fmaf(d0.x,a.x,fmaf(d0.y,a.y,fmaf(d0.z,a.z,a.w))),0.f);
    }
    ((float*)&ldsr[wslot][t])[lane] = racc;
    float degf = (float)(e1 - e0);
    accv[t] = fmaf(degf, b2l, hv);
  }
  __syncthreads();
  const float* wcol = w2 + lane;
  #pragma unroll 2
  for (int kq=0; kq<16; kq++){
    float w0 = wcol[(4*kq+0)*EMB];
    float w1v = wcol[(4*kq+1)*EMB];
    float w2v = wcol[(4*kq+2)*EMB];
    float w3 = wcol[(4*kq+3)*EMB];
    #pragma unroll
    for (int t=0;t<4;t++){
      float4 rv = ldsr[wslot][t][kq];
      accv[t] = fmaf(rv.x, w0, accv[t]);
      accv[t] = fmaf(rv.y, w1v, accv[t]);
      accv[t] = fmaf(rv.z, w2v, accv[t]);
      accv[t] = fmaf(rv.w, w3, accv[t]);
    }
  }
  #pragma unroll
  for (int t=0;t<4;t++)
    if (i0+t < n) hh16[(size_t)(i0+t)*EMB + lane] = f2bf(accv[t]);
}

// ---- fused per-layer stage 2: gather(bf16, 8-deep) + (hh+msg)@w1 + b1 -> y, + partial stats ----
__global__ __launch_bounds__(256) void k_l2(
  const unsigned short* __restrict__ hh16, const int* __restrict__ rs, const float* __restrict__ recw,
  const float* __restrict__ w1, const float* __restrict__ b1,
  float* __restrict__ y, float* __restrict__ pst, int n)
{
  __shared__ float4 ldsz[4][4][16];
  __shared__ float ls[128];
  int wv = (blockIdx.x*256 + threadIdx.x) >> 6;
  int wslot = (threadIdx.x >> 6) & 3;
  int lane = threadIdx.x & 63;
  int i0 = wv*4;
  if (threadIdx.x < 128) ls[threadIdx.x] = 0.f;
  #pragma unroll
  for (int t=0;t<4;t++){
    int i = i0 + t;
    bool act = (i < n);
    int ii = act ? i : 0;
    int e0 = rs[ii], e1 = rs[ii+1];
    float zc = bf2f(hh16[(size_t)ii*EMB + lane]);
    int e = e0;
    for (; e+8<=e1; e+=8){                  // 8 outstanding row-gathers (bf16 rows: 128B each)
      int s0 = (int)recw[4*(e+0)+3];
      int s1 = (int)recw[4*(e+1)+3];
      int s2 = (int)recw[4*(e+2)+3];
      int s3 = (int)recw[4*(e+3)+3];
      int s4 = (int)recw[4*(e+4)+3];
      int s5 = (int)recw[4*(e+5)+3];
      int s6 = (int)recw[4*(e+6)+3];
      int s7 = (int)recw[4*(e+7)+3];
      float g0 = bf2f(hh16[(size_t)s0*EMB + lane]);
      float g1 = bf2f(hh16[(size_t)s1*EMB + lane]);
      float g2 = bf2f(hh16[(size_t)s2*EMB + lane]);
      float g3 = bf2f(hh16[(size_t)s3*EMB + lane]);
      float g4 = bf2f(hh16[(size_t)s4*EMB + lane]);
      float g5 = bf2f(hh16[(size_t)s5*EMB + lane]);
      float g6 = bf2f(hh16[(size_t)s6*EMB + lane]);
      float g7 = bf2f(hh16[(size_t)s7*EMB + lane]);
      zc += ((g0+g1)+(g2+g3)) + ((g4+g5)+(g6+g7));
    }
    for (; e<e1; e++){
      int s0 = (int)recw[4*e+3];
      zc += bf2f(hh16[(size_t)s0*EMB + lane]);
    }
    ((float*)&ldsz[wslot][t])[lane] = zc;
  }
  __syncthreads();
  float b1l = b1[lane];
  float accv[4];
  #pragma unroll
  for (int t=0;t<4;t++) accv[t] = b1l;
  const float* wcol = w1 + lane;
  #pragma unroll 2
  for (int kq=0; kq<16; kq++){
    float w0 = wcol[(4*kq+0)*EMB];
    float w1v = wcol[(4*kq+1)*EMB];
    float w2v = wcol[(4*kq+2)*EMB];
    float w3 = wcol[(4*kq+3)*EMB];
    #pragma unroll
    for (int t=0;t<4;t++){
      float4 zv = ldsz[wslot][t][kq];
      accv[t] = fmaf(zv.x, w0, accv[t]);
      accv[t] = fmaf(zv.y, w1v, accv[t]);
      accv[t] = fmaf(zv.z, w2v, accv[t]);
      accv[t] = fmaf(zv.w, w3, accv[t]);
    }
  }
  float ssum = 0.f, ssq = 0.f;
  #pragma unroll
  for (int t=0;t<4;t++){
    if (i0+t < n){
      y[(size_t)(i0+t)*EMB + lane] = accv[t];
      ssum += accv[t];
      ssq = fmaf(accv[t], accv[t], ssq);
    }
  }
  atomicAdd(&ls[lane], ssum); atomicAdd(&ls[64+lane], ssq);
  __syncthreads();
  if (threadIdx.x < 128) pst[(size_t)blockIdx.x*128 + threadIdx.x] = ls[threadIdx.x];
}

// ---- per-layer stage 3: y = relu(bn1(y)) @ w2m + b2 (in place) + partial stats ----
__global__ __launch_bounds__(256) void k_l3(float* __restrict__ y,
  const float* __restrict__ st1, const float* __restrict__ g1, const float* __restrict__ be1,
  const float* __restrict__ w2, const float* __restrict__ b2,
  float* __restrict__ pst, int n, float invN)
{
  __shared__ float4 ldst[4][4][16];
  __shared__ float ls[128];
  int wv = (blockIdx.x*256 + threadIdx.x) >> 6;
  int wslot = (threadIdx.x >> 6) & 3;
  int lane = threadIdx.x & 63;
  int i0 = wv*4;
  if (threadIdx.x < 128) ls[threadIdx.x] = 0.f;
  float s1 = st1[lane*16], sq1 = st1[(64+lane)*16];
  float g1l = g1[lane], be1l = be1[lane];
  #pragma unroll
  for (int t=0;t<4;t++){
    int i = i0 + t;
    int ii = (i < n) ? i : 0;
    float yv = y[(size_t)ii*EMB + lane];
    ((float*)&ldst[wslot][t])[lane] = bnrelu(yv, s1, sq1, g1l, be1l, invN);
  }
  __syncthreads();
  float b2l = b2[lane];
  float accv[4];
  #pragma unroll
  for (int t=0;t<4;t++) accv[t] = b2l;
  const float* wcol = w2 + lane;
  #pragma unroll 2
  for (int kq=0; kq<16; kq++){
    float w0 = wcol[(4*kq+0)*EMB];
    float w1v = wcol[(4*kq+1)*EMB];
    float w2v = wcol[(4*kq+2)*EMB];
    float w3 = wcol[(4*kq+3)*EMB];
    #pragma unroll
    for (int t=0;t<4;t++){
      float4 tv = ldst[wslot][t][kq];
      accv[t] = fmaf(tv.x, w0, accv[t]);
      accv[t] = fmaf(tv.y, w1v, accv[t]);
      accv[t] = fmaf(tv.z, w2v, accv[t]);
      accv[t] = fmaf(tv.w, w3, accv[t]);
    }
  }
  float ssum = 0.f, ssq = 0.f;
  #pragma unroll
  for (int t=0;t<4;t++){
    if (i0+t < n){
      y[(size_t)(i0+t)*EMB + lane] = accv[t];
      ssum += accv[t];
      ssq = fmaf(accv[t], accv[t], ssq);
    }
  }
  atomicAdd(&ls[lane], ssum); atomicAdd(&ls[64+lane], ssq);
  __syncthreads();
  if (threadIdx.x < 128) pst[(size_t)blockIdx.x*128 + threadIdx.x] = ls[threadIdx.x];
}

// ---- reduce per-block partials: one block per channel-slot (0..127) ----
__global__ __launch_bounds__(256) void k_red(const float* __restrict__ pst,
    float* __restrict__ st, int nb)
{
  int ch = blockIdx.x;
  float s = 0.f;
  for (int i=threadIdx.x; i<nb; i+=256) s += pst[(size_t)i*128 + ch];
  #pragma unroll
  for (int off=32; off>0; off>>=1) s += __shfl_down(s, off);
  __shared__ float ws[4];
  if ((threadIdx.x&63)==0) ws[threadIdx.x>>6] = s;
  __syncthreads();
  if (threadIdx.x==0) st[ch*16] = ws[0]+ws[1]+ws[2]+ws[3];
}

// ---- final: h4 = h3 + relu(bn2(y)); out = h4 . wp + bp ----
__global__ __launch_bounds__(256) void k_out(
  const float* __restrict__ h, const float* __restrict__ y,
  const float* __restrict__ st2, const float* __restrict__ g2, const float* __restrict__ be2,
  const float* __restrict__ wp, const float* __restrict__ bp,
  float* __restrict__ out, int n, float invN)
{
  int i = blockIdx.x*256 + threadIdx.x; if (i>=n) return;
  const float* hr = h + (size_t)i*EMB;
  const float* yr = y + (size_t)i*EMB;
  float acc = 0.f;
  #pragma unroll
  for (int q=0;q<16;q++){
    int c0=q*4;
    float4 hv = *(const float4*)(hr+c0);
    float4 yv = *(const float4*)(yr+c0);
    float f0 = hv.x + bnrelu(yv.x, st2[(c0+0)*16], st2[(64+c0+0)*16], g2[c0+0], be2[c0+0], invN);
    float f1 = hv.y + bnrelu(yv.y, st2[(c0+1)*16], st2[(64+c0+1)*16], g2[c0+1], be2[c0+1], invN);
    float f2 = hv.z + bnrelu(yv.z, st2[(c0+2)*16], st2[(64+c0+2)*16], g2[c0+2], be2[c0+2], invN);
    float f3 = hv.w + bnrelu(yv.w, st2[(c0+3)*16], st2[(64+c0+3)*16], g2[c0+3], be2[c0+3], invN);
    acc = fmaf(f0, wp[c0+0], acc);
    acc = fmaf(f1, wp[c0+1], acc);
    acc = fmaf(f2, wp[c0+2], acc);
    acc = fmaf(f3, wp[c0+3], acc);
  }
  out[i] = acc + bp[0];
}

extern "C" void kernel_launch(void* const* d_in, const int* in_sizes, int n_in,
                              void* d_out, int out_size, void* d_ws, size_t ws_size,
                              hipStream_t stream)
{
  const float* x        = (const float*)d_in[0];
  const int*   ei       = (const int*)d_in[1];
  const float* ea       = (const float*)d_in[2];
  const float* lin_in_w = (const float*)d_in[3];
  const float* lin_in_b = (const float*)d_in[4];
  const float* ee_w1    = (const float*)d_in[5];
  const float* ee_b1    = (const float*)d_in[6];
  const float* ee_g1    = (const float*)d_in[7];
  const float* ee_be1   = (const float*)d_in[8];
  const float* ee_w2    = (const float*)d_in[9];
  const float* ee_b2    = (const float*)d_in[10];
  const float* mlp_w1   = (const float*)d_in[11];
  const float* mlp_b1   = (const float*)d_in[12];
  const float* mlp_g1   = (const float*)d_in[13];
  const float* mlp_be1  = (const float*)d_in[14];
  const float* mlp_w2   = (const float*)d_in[15];
  const float* mlp_b2   = (const float*)d_in[16];
  const float* mlp_g2   = (const float*)d_in[17];
  const float* mlp_be2  = (const float*)d_in[18];
  const float* pred_w   = (const float*)d_in[19];
  const float* pred_b   = (const float*)d_in[20];

  int n = in_sizes[0] / INDIM;
  int E = in_sizes[1] / 2;
  const int* srcp = ei;
  const int* dstp = ei + E;

  char* w = (char*)d_ws;
  auto al = [](size_t o){ return (o + 255) & ~(size_t)255; };
  size_t o = 0;
  int*   deg = (int*)(w + o);  o += (size_t)n*4;  o = al(o);
  float* est = (float*)(w + o); o += 144*4;  o = al(o);
  size_t zero_bytes = o;
  o = al(o); float* nst = (float*)(w + o); o += (size_t)NL*2*2048*4;  // st1/st2 per layer (16-padded)
  o = al(o); int* rs   = (int*)(w + o);   o += (size_t)(n+1)*4;
  o = al(o); int* bsum = (int*)(w + o);   o += 256*4;
  o = al(o); int* boff = (int*)(w + o);   o += 256*4;
  o = al(o); int* rank = (int*)(w + o);   o += (size_t)E*4;
  o = al(o); float4* rec = (float4*)(w + o); o += (size_t)E*16;
  o = al(o); float* acb = (float*)(w + o); o += (size_t)NL*256*4;
  o = al(o); float* h   = (float*)(w + o); o += (size_t)n*EMB*4;
  o = al(o); unsigned short* hh16 = (unsigned short*)(w + o); o += (size_t)n*EMB*2;
  o = al(o); float* yb  = (float*)(w + o); o += (size_t)n*EMB*4;
  o = al(o); float* pst = (float*)(w + o); o += (size_t)4096*128*4;

  (void)hipMemsetAsync(d_ws, 0, zero_bytes, stream);

  int nbChunk = (n + 1023)/1024;
  k_pass1<<<512, 256, 0, stream>>>(dstp, ea, E, deg, rank, est);
  k_scanA<<<nbChunk, 256, 0, stream>>>(deg, bsum, n);
  k_scanB<<<1, 64, 0, stream>>>(bsum, boff, rs, nbChunk, n);
  k_scanC<<<nbChunk, 256, 0, stream>>>(deg, boff, rs, n);
  k_scatter<<<1024, 256, 0, stream>>>(srcp, dstp, ea, E, rs, rank, rec);
  k_prec<<<1, 256, 0, stream>>>(est, ee_w1, ee_b1, ee_g1, ee_be1, acb, 1.f/(float)E);

  int nb_h0 = ((n + 7)/8 + 3)/4;        // 8 nodes/wave, 4 waves/block
  int nb_l  = (n + 15)/16;              // 4 nodes/wave, 4 waves/block
  float invN = 1.f/(float)n;
  k_h0<<<nb_h0, 256, 0, stream>>>(x, lin_in_w, lin_in_b, h, n);

  for (int l=0; l<NL; l++){
    float* st1 = nst + (size_t)l*4096;
    float* st2 = st1 + 2048;
    const float* st2prev = (l>0) ? (nst + (size_t)(l-1)*4096 + 2048) : nst;
    const float* g2p  = (l>0) ? (mlp_g2  + (size_t)(l-1)*64) : mlp_g2;
    const float* be2p = (l>0) ? (mlp_be2 + (size_t)(l-1)*64) : mlp_be2;
    k_l1<<<nb_l, 256, 0, stream>>>(h, hh16, yb, rs, rec,
        acb + (size_t)l*256, ee_w2 + (size_t)l*4096, ee_b2 + (size_t)l*64,
        st2prev, g2p, be2p, n, (l>0)?1:0, invN);
    k_l2<<<nb_l, 256, 0, stream>>>(hh16, rs, (const float*)rec,
        mlp_w1 + (size_t)l*4096, mlp_b1 + (size_t)l*64, yb, pst, n);
    k_red<<<128, 256, 0, stream>>>(pst, st1, nb_l);
    k_l3<<<nb_l, 256, 0, stream>>>(yb, st1,
        mlp_g1 + (size_t)l*64, mlp_be1 + (size_t)l*64,
        mlp_w2 + (size_t)l*4096, mlp_b2 + (size_t)l*64, pst, n, invN);
    k_red<<<128, 256, 0, stream>>>(pst, st2, nb_l);
  }
  k_out<<<(n+255)/256, 256, 0, stream>>>(h, yb,
      nst + (size_t)(NL-1)*4096 + 2048, mlp_g2 + (size_t)(NL-1)*64, mlp_be2 + (size_t)(NL-1)*64,
      pred_w, pred_b, (float*)d_out, n, invN);
}